// Round 16
// baseline (120.358 us; speedup 1.0000x reference)
//
#include <hip/hip_runtime.h>
#include <hip/hip_bf16.h>
#include <type_traits>

typedef __bf16 bf16_t;
typedef __bf16 bf16x4 __attribute__((ext_vector_type(4)));
typedef __bf16 bf16x8 __attribute__((ext_vector_type(8)));
typedef float  f32x4  __attribute__((ext_vector_type(4)));

__device__ __forceinline__ f32x4 mfma16(bf16x8 a, bf16x8 b, f32x4 c) {
  return __builtin_amdgcn_mfma_f32_16x16x32_bf16(a, b, c, 0, 0, 0);
}

static constexpr int NB = 8;
static constexpr int LQ = 1024;
static constexpr int LKk = 1024;
static constexpr int DMODEL = 512;
static constexpr int NH = 8;
static constexpr int DKH = 64;
static constexpr int MROWS = NB * LQ;   // 8192
static constexpr int MWORDS = NB * LQ * (LKk / 64);  // 131072 u64 words
#define KSCALE 0.1803368801111204f

// swizzled byte offset for [R][128B] row-major LDS tiles (G4 XOR swizzle)
__device__ __forceinline__ int swz(int row, int byte) {
  return row * 128 + (byte ^ ((row & 7) << 4));
}

// ------- mask bit-pack: one u64 word per THREAD, 16 independent int4 loads --
__global__ __launch_bounds__(256)
void mask_pack(const int* __restrict__ mask, unsigned long long* __restrict__ mpk) {
  const int wd = blockIdx.x * 256 + threadIdx.x;
  const int4* base = reinterpret_cast<const int4*>(mask + (size_t)wd * 64);
  unsigned long long bits = 0;
  #pragma unroll
  for (int i = 0; i < 16; ++i) {
    int4 v = base[i];
    bits |= (unsigned long long)(v.x != 0) << (4 * i);
    bits |= (unsigned long long)(v.y != 0) << (4 * i + 1);
    bits |= (unsigned long long)(v.z != 0) << (4 * i + 2);
    bits |= (unsigned long long)(v.w != 0) << (4 * i + 3);
  }
  mpk[wd] = bits;
}

// ------- one-time weight transpose+convert: W f32 [K][N] -> Wt bf16 [N][K] --
__device__ __forceinline__ void wt_tile(const float* __restrict__ W, bf16_t* __restrict__ Wt,
                                        int K, int N, int kt, int nt, int t) {
  __shared__ bf16_t T[64][72];
  const int k0 = kt * 64, n0 = nt * 64;
  const int kr = t >> 2, c0 = (t & 3) * 16;
  const float4* src = reinterpret_cast<const float4*>(W + (size_t)(k0 + kr) * N + n0 + c0);
  #pragma unroll
  for (int j = 0; j < 4; ++j) {
    float4 f = src[j];
    T[c0 + j * 4 + 0][kr] = (bf16_t)f.x;
    T[c0 + j * 4 + 1][kr] = (bf16_t)f.y;
    T[c0 + j * 4 + 2][kr] = (bf16_t)f.z;
    T[c0 + j * 4 + 3][kr] = (bf16_t)f.w;
  }
  __syncthreads();
  const int nr = t >> 2, kc0 = (t & 3) * 16;
  bf16_t* dst = Wt + (size_t)(n0 + nr) * K + k0 + kc0;
  #pragma unroll
  for (int j = 0; j < 2; ++j)
    *reinterpret_cast<bf16x8*>(dst + j * 8) =
        *reinterpret_cast<const bf16x8*>(&T[nr][kc0 + j * 8]);
}

__global__ __launch_bounds__(256)
void weight_prep(const float* __restrict__ Wq, const float* __restrict__ Wk,
                 const float* __restrict__ Wv, const float* __restrict__ Wo,
                 bf16_t* __restrict__ Wtq, bf16_t* __restrict__ Wtk,
                 bf16_t* __restrict__ Wtv, bf16_t* __restrict__ Wto) {
  const int bidx = blockIdx.x, t = threadIdx.x;
  if (bidx < 32)        wt_tile(Wq, Wtq, 256, 512, bidx >> 3, bidx & 7, t);
  else if (bidx < 64)   wt_tile(Wk, Wtk, 256, 512, (bidx - 32) >> 3, bidx & 7, t);
  else if (bidx < 96)   wt_tile(Wv, Wtv, 256, 512, (bidx - 64) >> 3, bidx & 7, t);
  else                  wt_tile(Wo, Wto, 512, 512, (bidx - 96) >> 3, bidx & 7, t);
}

// ---- GEMM (R14-proven 64^2 tile, 1024 blocks): C = postscale*act(A@Wt^T+b) --
template<int K, bool RELU, typename AT, typename OT>
__global__ __launch_bounds__(256)
void gemm_bias_act(const AT* __restrict__ A, const bf16_t* __restrict__ Wt,
                   const float* __restrict__ bias, OT* __restrict__ C,
                   float postscale)
{
  constexpr int N = 512;
  __shared__ alignas(16) char Alds[64 * 128];
  __shared__ alignas(16) char Wlds[64 * 128];
  const int t = threadIdx.x;
  const int l = t & 63, w = t >> 6;
  const int xcd = blockIdx.x & 7, idx = blockIdx.x >> 3;
  const int m0 = (xcd * 16 + (idx >> 3)) * 64, n0 = (idx & 7) * 64;

  f32x4 acc[4] = {};
  for (int k0 = 0; k0 < K; k0 += 64) {
    __syncthreads();
    if constexpr (std::is_same<AT, float>::value) {
      const int row = t >> 2, c0 = (t & 3) * 16;
      const float4* ap = reinterpret_cast<const float4*>(A + (size_t)(m0 + row) * K + k0 + c0);
      #pragma unroll
      for (int j = 0; j < 4; ++j) {
        float4 f = ap[j];
        bf16x4 o = { (bf16_t)f.x, (bf16_t)f.y, (bf16_t)f.z, (bf16_t)f.w };
        *reinterpret_cast<bf16x4*>(&Alds[swz(row, (c0 + j * 4) * 2)]) = o;
      }
    } else {
      const int row = t >> 2, cb = ((2 * t) & 7) * 16;
      const bf16_t* src = A + (size_t)(m0 + row) * K + k0 + cb / 2;
      *reinterpret_cast<bf16x8*>(&Alds[swz(row, cb)]) = *reinterpret_cast<const bf16x8*>(src);
      *reinterpret_cast<bf16x8*>(&Alds[swz(row, cb + 16)]) = *reinterpret_cast<const bf16x8*>(src + 8);
    }
    {
      const int row = t >> 2, cb = ((2 * t) & 7) * 16;
      const bf16_t* src = Wt + (size_t)(n0 + row) * K + k0 + cb / 2;
      *reinterpret_cast<bf16x8*>(&Wlds[swz(row, cb)]) = *reinterpret_cast<const bf16x8*>(src);
      *reinterpret_cast<bf16x8*>(&Wlds[swz(row, cb + 16)]) = *reinterpret_cast<const bf16x8*>(src + 8);
    }
    __syncthreads();
    #pragma unroll
    for (int ks = 0; ks < 2; ++ks) {
      const int kb = (ks * 32 + ((l >> 4) * 8)) * 2;
      const int arow = w * 16 + (l & 15);
      bf16x8 af = *reinterpret_cast<const bf16x8*>(&Alds[swz(arow, kb)]);
      #pragma unroll
      for (int ct = 0; ct < 4; ++ct) {
        const int brow = ct * 16 + (l & 15);
        bf16x8 bfr = *reinterpret_cast<const bf16x8*>(&Wlds[swz(brow, kb)]);
        acc[ct] = mfma16(af, bfr, acc[ct]);
      }
    }
  }
  #pragma unroll
  for (int ct = 0; ct < 4; ++ct) {
    const int col = n0 + ct * 16 + (l & 15);
    const float bv = bias[col];
    #pragma unroll
    for (int r = 0; r < 4; ++r) {
      const int row = m0 + w * 16 + ((l >> 4) * 4) + r;
      float x = acc[ct][r] + bv;
      if constexpr (RELU) x = fmaxf(x, 0.f);
      C[(size_t)row * N + col] = (OT)(x * postscale);
    }
  }
}

// ------- merged K+V projection (R14-proven); V written TRANSPOSED -----------
__global__ __launch_bounds__(256)
void gemm_kv(const float* __restrict__ A, const bf16_t* __restrict__ Wtk,
             const bf16_t* __restrict__ Wtv, const float* __restrict__ bk,
             const float* __restrict__ bv, bf16_t* __restrict__ Ck,
             bf16_t* __restrict__ Vt)
{
  constexpr int K = 256, N = 512;
  __shared__ alignas(16) char Alds[64 * 128];
  __shared__ alignas(16) char Wk_lds[64 * 128];
  __shared__ alignas(16) char Wv_lds[64 * 128];
  const int t = threadIdx.x;
  const int l = t & 63, w = t >> 6;
  const int xcd = blockIdx.x & 7, idx = blockIdx.x >> 3;
  const int m0 = (xcd * 16 + (idx >> 3)) * 64, n0 = (idx & 7) * 64;

  f32x4 acck[4] = {}, accv[4] = {};
  for (int k0 = 0; k0 < K; k0 += 64) {
    __syncthreads();
    {
      const int row = t >> 2, c0 = (t & 3) * 16;
      const float4* ap = reinterpret_cast<const float4*>(A + (size_t)(m0 + row) * K + k0 + c0);
      #pragma unroll
      for (int j = 0; j < 4; ++j) {
        float4 f = ap[j];
        bf16x4 o = { (bf16_t)f.x, (bf16_t)f.y, (bf16_t)f.z, (bf16_t)f.w };
        *reinterpret_cast<bf16x4*>(&Alds[swz(row, (c0 + j * 4) * 2)]) = o;
      }
    }
    {
      const int row = t >> 2, cb = ((2 * t) & 7) * 16;
      const bf16_t* sk = Wtk + (size_t)(n0 + row) * K + k0 + cb / 2;
      const bf16_t* sv = Wtv + (size_t)(n0 + row) * K + k0 + cb / 2;
      *reinterpret_cast<bf16x8*>(&Wk_lds[swz(row, cb)]) = *reinterpret_cast<const bf16x8*>(sk);
      *reinterpret_cast<bf16x8*>(&Wk_lds[swz(row, cb + 16)]) = *reinterpret_cast<const bf16x8*>(sk + 8);
      *reinterpret_cast<bf16x8*>(&Wv_lds[swz(row, cb)]) = *reinterpret_cast<const bf16x8*>(sv);
      *reinterpret_cast<bf16x8*>(&Wv_lds[swz(row, cb + 16)]) = *reinterpret_cast<const bf16x8*>(sv + 8);
    }
    __syncthreads();
    #pragma unroll
    for (int ks = 0; ks < 2; ++ks) {
      const int kb = (ks * 32 + ((l >> 4) * 8)) * 2;
      const int arow = w * 16 + (l & 15);
      bf16x8 af = *reinterpret_cast<const bf16x8*>(&Alds[swz(arow, kb)]);
      #pragma unroll
      for (int ct = 0; ct < 4; ++ct) {
        const int brow = ct * 16 + (l & 15);
        bf16x8 bk8 = *reinterpret_cast<const bf16x8*>(&Wk_lds[swz(brow, kb)]);
        bf16x8 bv8 = *reinterpret_cast<const bf16x8*>(&Wv_lds[swz(brow, kb)]);
        acck[ct] = mfma16(af, bk8, acck[ct]);
        accv[ct] = mfma16(af, bv8, accv[ct]);
      }
    }
  }
  const int row0 = m0 + w * 16 + ((l >> 4) * 4);
  const int vb = row0 >> 10;
  const int kv = row0 & 1023;
  #pragma unroll
  for (int ct = 0; ct < 4; ++ct) {
    const int col = n0 + ct * 16 + (l & 15);
    const float bkv = bk[col], bvv = bv[col];
    #pragma unroll
    for (int r = 0; r < 4; ++r)
      Ck[(size_t)(row0 + r) * N + col] = (bf16_t)(fmaxf(acck[ct][r] + bkv, 0.f) * KSCALE);
    bf16x4 vv;
    #pragma unroll
    for (int r = 0; r < 4; ++r) vv[r] = (bf16_t)fmaxf(accv[ct][r] + bvv, 0.f);
    bf16_t* dst = Vt + (((size_t)vb * NH + (col >> 6)) * DKH + (col & 63)) * LKk + kv;
    *reinterpret_cast<bf16x4*>(dst) = vv;
  }
}

// -- flash attention v4: BARRIER-FREE. K/V fragments loaded directly from
//    global (L2-resident per (b,h): 128KB each; Vt pre-transposed so both are
//    contiguous 16B loads). LDS holds only per-wave P. Guide CM#7 / m169.
__global__ __launch_bounds__(256)
void attn_kernel(const bf16_t* __restrict__ Qp, const bf16_t* __restrict__ Kp,
                 const bf16_t* __restrict__ Vt, const unsigned long long* __restrict__ Mpk,
                 bf16_t* __restrict__ AO)
{
  __shared__ alignas(16) char Plds[4 * 32 * 128];   // per-wave [32 q][64 kv]
  const int t = threadIdx.x, l = t & 63, w = t >> 6;
  const int g = l >> 4, qh = l & 15;
  const int bid = (blockIdx.x & 7) * 64 + (blockIdx.x >> 3);
  const int qt = bid & 7, h = (bid >> 3) & 7, b = bid >> 6;
  const int wq0 = qt * 128 + w * 32;
  const size_t rb = (size_t)b * LQ;
  const bf16_t* vtb = Vt + ((size_t)b * NH + h) * DKH * LKk;

  bf16x8 qf[2][2];
  #pragma unroll
  for (int j = 0; j < 2; ++j)
    #pragma unroll
    for (int ks = 0; ks < 2; ++ks)
      qf[j][ks] = *reinterpret_cast<const bf16x8*>(
          Qp + (rb + wq0 + j * 16 + qh) * DMODEL + h * DKH + ks * 32 + g * 8);

  const unsigned long long* mrow0 = Mpk + (rb + wq0 + qh) * (LKk / 64);
  const unsigned long long* mrow1 = Mpk + (rb + wq0 + 16 + qh) * (LKk / 64);

  // per-lane fragment source bases
  const bf16_t* kfb = Kp + (rb + qh) * DMODEL + h * DKH + g * 8;   // + kv-terms
  const bf16_t* vfb = vtb + (size_t)qh * LKk + g * 8;              // + dct*16*LKk + kv0

  f32x4 acc[2][4] = {};
  float mrun[2] = { -1e30f, -1e30f }, lsum[2] = { 0.f, 0.f };

  for (int kv0 = 0; kv0 < LKk; kv0 += 64) {
    const unsigned long long mw[2] = { mrow0[kv0 >> 6], mrow1[kv0 >> 6] };

    // S^T = mfma(A=K, B=Q[j]); K-frags straight from global (16B contiguous)
    f32x4 s[2][4] = {};
    #pragma unroll
    for (int ks = 0; ks < 2; ++ks) {
      #pragma unroll
      for (int ct = 0; ct < 4; ++ct) {
        bf16x8 kf = *reinterpret_cast<const bf16x8*>(
            kfb + (size_t)(kv0 + ct * 16) * DMODEL + ks * 32);
        s[0][ct] = mfma16(kf, qf[0][ks], s[0][ct]);
        s[1][ct] = mfma16(kf, qf[1][ks], s[1][ct]);
      }
    }

    #pragma unroll
    for (int j = 0; j < 2; ++j) {
      float rmax = -1e30f;
      #pragma unroll
      for (int ct = 0; ct < 4; ++ct) {
        #pragma unroll
        for (int r = 0; r < 4; ++r) {
          float x = ((mw[j] >> (ct * 16 + g * 4 + r)) & 1) ? s[j][ct][r] : -1e8f;
          s[j][ct][r] = x;
          rmax = fmaxf(rmax, x);
        }
      }
      rmax = fmaxf(rmax, __shfl_xor(rmax, 16));
      rmax = fmaxf(rmax, __shfl_xor(rmax, 32));
      const float newm = fmaxf(mrun[j], rmax);

      if (__any(newm > mrun[j])) {
        const float scale = __builtin_amdgcn_exp2f(mrun[j] - newm);
        lsum[j] *= scale;
        #pragma unroll
        for (int r = 0; r < 4; ++r) {
          const float sr = __shfl(scale, g * 4 + r, 64);
          #pragma unroll
          for (int dct = 0; dct < 4; ++dct) acc[j][dct][r] *= sr;
        }
        mrun[j] = newm;
      }

      float psum = 0.f;
      #pragma unroll
      for (int ct = 0; ct < 4; ++ct) {
        #pragma unroll
        for (int r = 0; r < 4; ++r) {
          const float pv = __builtin_amdgcn_exp2f(s[j][ct][r] - mrun[j]);
          s[j][ct][r] = pv;
          psum += pv;
        }
      }
      psum += __shfl_xor(psum, 16);
      psum += __shfl_xor(psum, 32);
      lsum[j] += psum;

      // P writes — per-wave LDS slice, SCALAR bf16 stores (curse rule);
      // same-wave write->read needs no barrier (lgkmcnt handles ordering)
      #pragma unroll
      for (int ct = 0; ct < 4; ++ct) {
        #pragma unroll
        for (int r = 0; r < 4; ++r)
          *reinterpret_cast<bf16_t*>(
              &Plds[w * 4096 + swz(j * 16 + qh, (ct * 16 + g * 4 + r) * 2)]) =
              (bf16_t)s[j][ct][r];
      }
    }

    // O += P V; V-frags straight from pre-transposed Vt (16B contiguous)
    #pragma unroll
    for (int ks = 0; ks < 2; ++ks) {
      const int kb = (ks * 32 + g * 8) * 2;
      bf16x8 pf0 = *reinterpret_cast<const bf16x8*>(&Plds[w * 4096 + swz(qh, kb)]);
      bf16x8 pf1 = *reinterpret_cast<const bf16x8*>(&Plds[w * 4096 + swz(16 + qh, kb)]);
      #pragma unroll
      for (int dct = 0; dct < 4; ++dct) {
        bf16x8 vf = *reinterpret_cast<const bf16x8*>(
            vfb + (size_t)(dct * 16) * LKk + kv0 + ks * 32);
        acc[0][dct] = mfma16(pf0, vf, acc[0][dct]);
        acc[1][dct] = mfma16(pf1, vf, acc[1][dct]);
      }
    }
  }

  #pragma unroll
  for (int j = 0; j < 2; ++j) {
    const float inv = 1.0f / lsum[j];
    float invr[4];
    #pragma unroll
    for (int r = 0; r < 4; ++r) invr[r] = __shfl(inv, g * 4 + r, 64);
    #pragma unroll
    for (int dct = 0; dct < 4; ++dct) {
      const int col = h * DKH + dct * 16 + qh;
      #pragma unroll
      for (int r = 0; r < 4; ++r) {
        const int q = wq0 + j * 16 + g * 4 + r;
        AO[(rb + q) * DMODEL + col] = (bf16_t)(acc[j][dct][r] * invr[r]);
      }
    }
  }
}

extern "C" void kernel_launch(void* const* d_in, const int* in_sizes, int n_in,
                              void* d_out, int out_size, void* d_ws, size_t ws_size,
                              hipStream_t stream)
{
  const float* query = (const float*)d_in[0];
  const float* keyin = (const float*)d_in[1];
  const int*   mask  = (const int*)d_in[2];
  const float* Wq = (const float*)d_in[3];
  const float* bq = (const float*)d_in[4];
  const float* Wk = (const float*)d_in[5];
  const float* bk = (const float*)d_in[6];
  const float* Wv = (const float*)d_in[7];
  const float* bv = (const float*)d_in[8];
  const float* Wo = (const float*)d_in[9];
  const float* bo = (const float*)d_in[10];
  float* out = (float*)d_out;

  bf16_t* Qp = (bf16_t*)d_ws;
  bf16_t* Kp = Qp + (size_t)MROWS * DMODEL;
  bf16_t* Vt = Kp + (size_t)MROWS * DMODEL;
  bf16_t* AO = Vt + (size_t)MROWS * DMODEL;
  unsigned long long* Mpk = (unsigned long long*)(AO + (size_t)MROWS * DMODEL);
  bf16_t* Wtq = (bf16_t*)(Mpk + MWORDS);
  bf16_t* Wtk = Wtq + 512 * 256;
  bf16_t* Wtv = Wtk + 512 * 256;
  bf16_t* Wto = Wtv + 512 * 256;

  dim3 blk(256);

  weight_prep<<<dim3(160), blk, 0, stream>>>(Wq, Wk, Wv, Wo, Wtq, Wtk, Wtv, Wto);
  mask_pack<<<dim3(MWORDS / 256), blk, 0, stream>>>(mask, Mpk);
  gemm_bias_act<256, true, float, bf16_t><<<dim3(1024), blk, 0, stream>>>(query, Wtq, bq, Qp, 1.0f);
  gemm_kv<<<dim3(1024), blk, 0, stream>>>(keyin, Wtk, Wtv, bk, bv, Kp, Vt);

  attn_kernel<<<dim3(NB * NH * (LQ / 128)), blk, 0, stream>>>(Qp, Kp, Vt, Mpk, AO);

  gemm_bias_act<512, false, bf16_t, float><<<dim3(1024), blk, 0, stream>>>(AO, Wto, bo, out, 1.0f);
}

// Round 19
// 116.572 us; speedup vs baseline: 1.0325x; 1.0325x over previous
//
#include <hip/hip_runtime.h>
#include <hip/hip_bf16.h>
#include <type_traits>

typedef __bf16 bf16_t;
typedef __bf16 bf16x4 __attribute__((ext_vector_type(4)));
typedef __bf16 bf16x8 __attribute__((ext_vector_type(8)));
typedef float  f32x4  __attribute__((ext_vector_type(4)));

__device__ __forceinline__ f32x4 mfma16(bf16x8 a, bf16x8 b, f32x4 c) {
  return __builtin_amdgcn_mfma_f32_16x16x32_bf16(a, b, c, 0, 0, 0);
}

static constexpr int NB = 8;
static constexpr int LQ = 1024;
static constexpr int LKk = 1024;
static constexpr int DMODEL = 512;
static constexpr int NH = 8;
static constexpr int DKH = 64;
static constexpr int MROWS = NB * LQ;   // 8192
static constexpr int MWORDS = NB * LQ * (LKk / 64);  // 131072 u64 words
#define KSCALE 0.1803368801111204f

// swizzled byte offset for [R][128B] row-major LDS tiles (G4 XOR swizzle)
__device__ __forceinline__ int swz(int row, int byte) {
  return row * 128 + (byte ^ ((row & 7) << 4));
}

// ------- mask bit-pack: one u64 word per THREAD, 16 independent int4 loads --
__global__ __launch_bounds__(256)
void mask_pack(const int* __restrict__ mask, unsigned long long* __restrict__ mpk) {
  const int wd = blockIdx.x * 256 + threadIdx.x;
  const int4* base = reinterpret_cast<const int4*>(mask + (size_t)wd * 64);
  unsigned long long bits = 0;
  #pragma unroll
  for (int i = 0; i < 16; ++i) {
    int4 v = base[i];
    bits |= (unsigned long long)(v.x != 0) << (4 * i);
    bits |= (unsigned long long)(v.y != 0) << (4 * i + 1);
    bits |= (unsigned long long)(v.z != 0) << (4 * i + 2);
    bits |= (unsigned long long)(v.w != 0) << (4 * i + 3);
  }
  mpk[wd] = bits;
}

// ------- one-time weight transpose+convert: W f32 [K][N] -> Wt bf16 [N][K] --
__device__ __forceinline__ void wt_tile(const float* __restrict__ W, bf16_t* __restrict__ Wt,
                                        int K, int N, int kt, int nt, int t) {
  __shared__ bf16_t T[64][72];
  const int k0 = kt * 64, n0 = nt * 64;
  const int kr = t >> 2, c0 = (t & 3) * 16;
  const float4* src = reinterpret_cast<const float4*>(W + (size_t)(k0 + kr) * N + n0 + c0);
  #pragma unroll
  for (int j = 0; j < 4; ++j) {
    float4 f = src[j];
    T[c0 + j * 4 + 0][kr] = (bf16_t)f.x;
    T[c0 + j * 4 + 1][kr] = (bf16_t)f.y;
    T[c0 + j * 4 + 2][kr] = (bf16_t)f.z;
    T[c0 + j * 4 + 3][kr] = (bf16_t)f.w;
  }
  __syncthreads();
  const int nr = t >> 2, kc0 = (t & 3) * 16;
  bf16_t* dst = Wt + (size_t)(n0 + nr) * K + k0 + kc0;
  #pragma unroll
  for (int j = 0; j < 2; ++j)
    *reinterpret_cast<bf16x8*>(dst + j * 8) =
        *reinterpret_cast<const bf16x8*>(&T[nr][kc0 + j * 8]);
}

__global__ __launch_bounds__(256)
void weight_prep(const float* __restrict__ Wq, const float* __restrict__ Wk,
                 const float* __restrict__ Wv, const float* __restrict__ Wo,
                 bf16_t* __restrict__ Wtq, bf16_t* __restrict__ Wtk,
                 bf16_t* __restrict__ Wtv, bf16_t* __restrict__ Wto) {
  const int bidx = blockIdx.x, t = threadIdx.x;
  if (bidx < 32)        wt_tile(Wq, Wtq, 256, 512, bidx >> 3, bidx & 7, t);
  else if (bidx < 64)   wt_tile(Wk, Wtk, 256, 512, (bidx - 32) >> 3, bidx & 7, t);
  else if (bidx < 96)   wt_tile(Wv, Wtv, 256, 512, (bidx - 64) >> 3, bidx & 7, t);
  else                  wt_tile(Wo, Wto, 512, 512, (bidx - 96) >> 3, bidx & 7, t);
}

// ---- GEMM (R14-proven 64^2 tile, 1024 blocks): C = postscale*act(A@Wt^T+b) --
template<int K, bool RELU, typename AT, typename OT>
__global__ __launch_bounds__(256)
void gemm_bias_act(const AT* __restrict__ A, const bf16_t* __restrict__ Wt,
                   const float* __restrict__ bias, OT* __restrict__ C,
                   float postscale)
{
  constexpr int N = 512;
  __shared__ alignas(16) char Alds[64 * 128];
  __shared__ alignas(16) char Wlds[64 * 128];
  const int t = threadIdx.x;
  const int l = t & 63, w = t >> 6;
  const int xcd = blockIdx.x & 7, idx = blockIdx.x >> 3;
  const int m0 = (xcd * 16 + (idx >> 3)) * 64, n0 = (idx & 7) * 64;

  f32x4 acc[4] = {};
  for (int k0 = 0; k0 < K; k0 += 64) {
    __syncthreads();
    if constexpr (std::is_same<AT, float>::value) {
      const int row = t >> 2, c0 = (t & 3) * 16;
      const float4* ap = reinterpret_cast<const float4*>(A + (size_t)(m0 + row) * K + k0 + c0);
      #pragma unroll
      for (int j = 0; j < 4; ++j) {
        float4 f = ap[j];
        bf16x4 o = { (bf16_t)f.x, (bf16_t)f.y, (bf16_t)f.z, (bf16_t)f.w };
        *reinterpret_cast<bf16x4*>(&Alds[swz(row, (c0 + j * 4) * 2)]) = o;
      }
    } else {
      const int row = t >> 2, cb = ((2 * t) & 7) * 16;
      const bf16_t* src = A + (size_t)(m0 + row) * K + k0 + cb / 2;
      *reinterpret_cast<bf16x8*>(&Alds[swz(row, cb)]) = *reinterpret_cast<const bf16x8*>(src);
      *reinterpret_cast<bf16x8*>(&Alds[swz(row, cb + 16)]) = *reinterpret_cast<const bf16x8*>(src + 8);
    }
    {
      const int row = t >> 2, cb = ((2 * t) & 7) * 16;
      const bf16_t* src = Wt + (size_t)(n0 + row) * K + k0 + cb / 2;
      *reinterpret_cast<bf16x8*>(&Wlds[swz(row, cb)]) = *reinterpret_cast<const bf16x8*>(src);
      *reinterpret_cast<bf16x8*>(&Wlds[swz(row, cb + 16)]) = *reinterpret_cast<const bf16x8*>(src + 8);
    }
    __syncthreads();
    #pragma unroll
    for (int ks = 0; ks < 2; ++ks) {
      const int kb = (ks * 32 + ((l >> 4) * 8)) * 2;
      const int arow = w * 16 + (l & 15);
      bf16x8 af = *reinterpret_cast<const bf16x8*>(&Alds[swz(arow, kb)]);
      #pragma unroll
      for (int ct = 0; ct < 4; ++ct) {
        const int brow = ct * 16 + (l & 15);
        bf16x8 bfr = *reinterpret_cast<const bf16x8*>(&Wlds[swz(brow, kb)]);
        acc[ct] = mfma16(af, bfr, acc[ct]);
      }
    }
  }
  #pragma unroll
  for (int ct = 0; ct < 4; ++ct) {
    const int col = n0 + ct * 16 + (l & 15);
    const float bv = bias[col];
    #pragma unroll
    for (int r = 0; r < 4; ++r) {
      const int row = m0 + w * 16 + ((l >> 4) * 4) + r;
      float x = acc[ct][r] + bv;
      if constexpr (RELU) x = fmaxf(x, 0.f);
      C[(size_t)row * N + col] = (OT)(x * postscale);
    }
  }
}

// ------- merged K+V projection (R14-proven); V written TRANSPOSED -----------
__global__ __launch_bounds__(256)
void gemm_kv(const float* __restrict__ A, const bf16_t* __restrict__ Wtk,
             const bf16_t* __restrict__ Wtv, const float* __restrict__ bk,
             const float* __restrict__ bv, bf16_t* __restrict__ Ck,
             bf16_t* __restrict__ Vt)
{
  constexpr int K = 256, N = 512;
  __shared__ alignas(16) char Alds[64 * 128];
  __shared__ alignas(16) char Wk_lds[64 * 128];
  __shared__ alignas(16) char Wv_lds[64 * 128];
  const int t = threadIdx.x;
  const int l = t & 63, w = t >> 6;
  const int xcd = blockIdx.x & 7, idx = blockIdx.x >> 3;
  const int m0 = (xcd * 16 + (idx >> 3)) * 64, n0 = (idx & 7) * 64;

  f32x4 acck[4] = {}, accv[4] = {};
  for (int k0 = 0; k0 < K; k0 += 64) {
    __syncthreads();
    {
      const int row = t >> 2, c0 = (t & 3) * 16;
      const float4* ap = reinterpret_cast<const float4*>(A + (size_t)(m0 + row) * K + k0 + c0);
      #pragma unroll
      for (int j = 0; j < 4; ++j) {
        float4 f = ap[j];
        bf16x4 o = { (bf16_t)f.x, (bf16_t)f.y, (bf16_t)f.z, (bf16_t)f.w };
        *reinterpret_cast<bf16x4*>(&Alds[swz(row, (c0 + j * 4) * 2)]) = o;
      }
    }
    {
      const int row = t >> 2, cb = ((2 * t) & 7) * 16;
      const bf16_t* sk = Wtk + (size_t)(n0 + row) * K + k0 + cb / 2;
      const bf16_t* sv = Wtv + (size_t)(n0 + row) * K + k0 + cb / 2;
      *reinterpret_cast<bf16x8*>(&Wk_lds[swz(row, cb)]) = *reinterpret_cast<const bf16x8*>(sk);
      *reinterpret_cast<bf16x8*>(&Wk_lds[swz(row, cb + 16)]) = *reinterpret_cast<const bf16x8*>(sk + 8);
      *reinterpret_cast<bf16x8*>(&Wv_lds[swz(row, cb)]) = *reinterpret_cast<const bf16x8*>(sv);
      *reinterpret_cast<bf16x8*>(&Wv_lds[swz(row, cb + 16)]) = *reinterpret_cast<const bf16x8*>(sv + 8);
    }
    __syncthreads();
    #pragma unroll
    for (int ks = 0; ks < 2; ++ks) {
      const int kb = (ks * 32 + ((l >> 4) * 8)) * 2;
      const int arow = w * 16 + (l & 15);
      bf16x8 af = *reinterpret_cast<const bf16x8*>(&Alds[swz(arow, kb)]);
      #pragma unroll
      for (int ct = 0; ct < 4; ++ct) {
        const int brow = ct * 16 + (l & 15);
        bf16x8 bk8 = *reinterpret_cast<const bf16x8*>(&Wk_lds[swz(brow, kb)]);
        bf16x8 bv8 = *reinterpret_cast<const bf16x8*>(&Wv_lds[swz(brow, kb)]);
        acck[ct] = mfma16(af, bk8, acck[ct]);
        accv[ct] = mfma16(af, bv8, accv[ct]);
      }
    }
  }
  const int row0 = m0 + w * 16 + ((l >> 4) * 4);
  const int vb = row0 >> 10;
  const int kv = row0 & 1023;
  #pragma unroll
  for (int ct = 0; ct < 4; ++ct) {
    const int col = n0 + ct * 16 + (l & 15);
    const float bkv = bk[col], bvv = bv[col];
    #pragma unroll
    for (int r = 0; r < 4; ++r)
      Ck[(size_t)(row0 + r) * N + col] = (bf16_t)(fmaxf(acck[ct][r] + bkv, 0.f) * KSCALE);
    bf16x4 vv;
    #pragma unroll
    for (int r = 0; r < 4; ++r) vv[r] = (bf16_t)fmaxf(accv[ct][r] + bvv, 0.f);
    bf16_t* dst = Vt + (((size_t)vb * NH + (col >> 6)) * DKH + (col & 63)) * LKk + kv;
    *reinterpret_cast<bf16x4*>(dst) = vv;
  }
}

// ======= shared attention core (R14-verified) over a kv range ===============
// LDS layout (SM, 32 KB): K [0,8K) | V [8K,16K) | P [16K,32K). Plds = SM+16K.
// SPLIT: write raw f32 partial O + per-(q,HEAD) (m,l); else normalize -> AO.
template<bool SPLIT>
__device__ __forceinline__ void attn_core(
    const bf16_t* __restrict__ Qp, const bf16_t* __restrict__ Kp,
    const bf16_t* __restrict__ Vt, const unsigned long long* __restrict__ Mpk,
    bf16_t* __restrict__ AO, float* __restrict__ Od, float* __restrict__ ml,
    int b, int h, int qt, int kvbeg, int kvend, char* Plds)
{
  const int t = threadIdx.x, l = t & 63, w = t >> 6;
  const int g = l >> 4, qh = l & 15;
  const int wq0 = qt * 128 + w * 32;
  const size_t rb = (size_t)b * LQ;
  const bf16_t* vtb = Vt + ((size_t)b * NH + h) * DKH * LKk;

  bf16x8 qf[2][2];
  #pragma unroll
  for (int j = 0; j < 2; ++j)
    #pragma unroll
    for (int ks = 0; ks < 2; ++ks)
      qf[j][ks] = *reinterpret_cast<const bf16x8*>(
          Qp + (rb + wq0 + j * 16 + qh) * DMODEL + h * DKH + ks * 32 + g * 8);

  const unsigned long long* mrow0 = Mpk + (rb + wq0 + qh) * (LKk / 64);
  const unsigned long long* mrow1 = Mpk + (rb + wq0 + 16 + qh) * (LKk / 64);

  f32x4 acc[2][4] = {};
  float mrun[2] = { -1e30f, -1e30f }, lsum[2] = { 0.f, 0.f };

  for (int kv0 = kvbeg; kv0 < kvend; kv0 += 64) {
    const unsigned long long mw[2] = { mrow0[kv0 >> 6], mrow1[kv0 >> 6] };

    __syncthreads();
    {
      const int row = t >> 2, cb = ((2 * t) & 7) * 16;
      const bf16_t* src = Kp + (rb + kv0 + row) * DMODEL + h * DKH + cb / 2;
      *reinterpret_cast<bf16x8*>(&Plds[-16384 + swz(row, cb)]) = *reinterpret_cast<const bf16x8*>(src);
      *reinterpret_cast<bf16x8*>(&Plds[-16384 + swz(row, cb + 16)]) = *reinterpret_cast<const bf16x8*>(src + 8);
    }
    {
      const int row = t >> 2, cb = ((2 * t) & 7) * 16;
      const bf16_t* src = vtb + (size_t)row * LKk + kv0 + cb / 2;
      *reinterpret_cast<bf16x8*>(&Plds[-8192 + swz(row, cb)]) = *reinterpret_cast<const bf16x8*>(src);
      *reinterpret_cast<bf16x8*>(&Plds[-8192 + swz(row, cb + 16)]) = *reinterpret_cast<const bf16x8*>(src + 8);
    }
    __syncthreads();

    f32x4 s[2][4] = {};
    #pragma unroll
    for (int ks = 0; ks < 2; ++ks) {
      const int kb = (ks * 32 + g * 8) * 2;
      #pragma unroll
      for (int ct = 0; ct < 4; ++ct) {
        bf16x8 kf = *reinterpret_cast<const bf16x8*>(&Plds[-16384 + swz(ct * 16 + qh, kb)]);
        s[0][ct] = mfma16(kf, qf[0][ks], s[0][ct]);
        s[1][ct] = mfma16(kf, qf[1][ks], s[1][ct]);
      }
    }

    #pragma unroll
    for (int j = 0; j < 2; ++j) {
      float rmax = -1e30f;
      #pragma unroll
      for (int ct = 0; ct < 4; ++ct) {
        #pragma unroll
        for (int r = 0; r < 4; ++r) {
          float x = ((mw[j] >> (ct * 16 + g * 4 + r)) & 1) ? s[j][ct][r] : -1e8f;
          s[j][ct][r] = x;
          rmax = fmaxf(rmax, x);
        }
      }
      rmax = fmaxf(rmax, __shfl_xor(rmax, 16));
      rmax = fmaxf(rmax, __shfl_xor(rmax, 32));
      const float newm = fmaxf(mrun[j], rmax);

      if (__any(newm > mrun[j])) {
        const float scale = __builtin_amdgcn_exp2f(mrun[j] - newm);
        lsum[j] *= scale;
        #pragma unroll
        for (int r = 0; r < 4; ++r) {
          const float sr = __shfl(scale, g * 4 + r, 64);
          #pragma unroll
          for (int dct = 0; dct < 4; ++dct) acc[j][dct][r] *= sr;
        }
        mrun[j] = newm;
      }

      float psum = 0.f;
      #pragma unroll
      for (int ct = 0; ct < 4; ++ct) {
        #pragma unroll
        for (int r = 0; r < 4; ++r) {
          const float pv = __builtin_amdgcn_exp2f(s[j][ct][r] - mrun[j]);
          s[j][ct][r] = pv;
          psum += pv;
        }
      }
      psum += __shfl_xor(psum, 16);
      psum += __shfl_xor(psum, 32);
      lsum[j] += psum;

      #pragma unroll
      for (int ct = 0; ct < 4; ++ct) {
        #pragma unroll
        for (int r = 0; r < 4; ++r)
          *reinterpret_cast<bf16_t*>(
              &Plds[w * 4096 + swz(j * 16 + qh, (ct * 16 + g * 4 + r) * 2)]) =
              (bf16_t)s[j][ct][r];
      }
    }

    #pragma unroll
    for (int ks = 0; ks < 2; ++ks) {
      const int kb = (ks * 32 + g * 8) * 2;
      bf16x8 pf0 = *reinterpret_cast<const bf16x8*>(&Plds[w * 4096 + swz(qh, kb)]);
      bf16x8 pf1 = *reinterpret_cast<const bf16x8*>(&Plds[w * 4096 + swz(16 + qh, kb)]);
      #pragma unroll
      for (int dct = 0; dct < 4; ++dct) {
        bf16x8 vf = *reinterpret_cast<const bf16x8*>(&Plds[-8192 + swz(dct * 16 + qh, kb)]);
        acc[0][dct] = mfma16(pf0, vf, acc[0][dct]);
        acc[1][dct] = mfma16(pf1, vf, acc[1][dct]);
      }
    }
  }

  if constexpr (SPLIT) {
    #pragma unroll
    for (int j = 0; j < 2; ++j) {
      #pragma unroll
      for (int dct = 0; dct < 4; ++dct) {
        const int col = h * DKH + dct * 16 + qh;
        #pragma unroll
        for (int r = 0; r < 4; ++r) {
          const int q = wq0 + j * 16 + g * 4 + r;
          Od[(rb + q) * DMODEL + col] = acc[j][dct][r];
        }
      }
      if (g == 0) {
        // per-(q, HEAD) softmax state  (R18 bug: head index was missing)
        const size_t mi = ((rb + wq0 + j * 16 + qh) * NH + h) * 2;
        ml[mi]     = mrun[j];
        ml[mi + 1] = lsum[j];
      }
    }
  } else {
    #pragma unroll
    for (int j = 0; j < 2; ++j) {
      const float inv = 1.0f / lsum[j];
      float invr[4];
      #pragma unroll
      for (int r = 0; r < 4; ++r) invr[r] = __shfl(inv, g * 4 + r, 64);
      #pragma unroll
      for (int dct = 0; dct < 4; ++dct) {
        const int col = h * DKH + dct * 16 + qh;
        #pragma unroll
        for (int r = 0; r < 4; ++r) {
          const int q = wq0 + j * 16 + g * 4 + r;
          AO[(rb + q) * DMODEL + col] = (bf16_t)(acc[j][dct][r] * invr[r]);
        }
      }
    }
  }
}

// full-kv (fallback) — R14-identical behavior
__global__ __launch_bounds__(256)
void attn_kernel(const bf16_t* __restrict__ Qp, const bf16_t* __restrict__ Kp,
                 const bf16_t* __restrict__ Vt, const unsigned long long* __restrict__ Mpk,
                 bf16_t* __restrict__ AO)
{
  __shared__ alignas(16) char SM[32768];   // K 8K | V 8K | P 16K
  const int bid = (blockIdx.x & 7) * 64 + (blockIdx.x >> 3);
  const int qt = bid & 7, h = (bid >> 3) & 7, b = bid >> 6;
  attn_core<false>(Qp, Kp, Vt, Mpk, AO, nullptr, nullptr,
                   b, h, qt, 0, LKk, SM + 16384);
}

// kv-split: grid 1024, hw = kv-half; partial f32 output
__global__ __launch_bounds__(256)
void attn_split(const bf16_t* __restrict__ Qp, const bf16_t* __restrict__ Kp,
                const bf16_t* __restrict__ Vt, const unsigned long long* __restrict__ Mpk,
                float* __restrict__ O0, float* __restrict__ O1,
                float* __restrict__ ml0, float* __restrict__ ml1)
{
  __shared__ alignas(16) char SM[32768];   // K 8K | V 8K | P 16K
  const int raw = blockIdx.x;
  const int bid = (raw & 7) * 128 + (raw >> 3);   // XCD chunking over 1024
  const int hw = bid & 1;
  const int bid2 = bid >> 1;
  const int qt = bid2 & 7, h = (bid2 >> 3) & 7, b = bid2 >> 6;
  attn_core<true>(Qp, Kp, Vt, Mpk, nullptr,
                  hw ? O1 : O0, hw ? ml1 : ml0,
                  b, h, qt, hw * 512, hw * 512 + 512, SM + 16384);
}

// ------- out-projection with fused flash-combine A-staging -----------------
// Each k-tile (64 cols) of the K-dimension is exactly one head -> per-tile
// per-row combine weights from ml[row][head].
__global__ __launch_bounds__(256)
void gemm_out_combine(const float* __restrict__ O0, const float* __restrict__ O1,
                      const float* __restrict__ ml0, const float* __restrict__ ml1,
                      const bf16_t* __restrict__ Wt, const float* __restrict__ bias,
                      float* __restrict__ C)
{
  constexpr int K = 512, N = 512;
  __shared__ alignas(16) char Alds[64 * 128];
  __shared__ alignas(16) char Wlds[64 * 128];
  const int t = threadIdx.x;
  const int l = t & 63, w = t >> 6;
  const int xcd = blockIdx.x & 7, idx = blockIdx.x >> 3;
  const int m0 = (xcd * 16 + (idx >> 3)) * 64, n0 = (idx & 7) * 64;
  const int arow_g = m0 + (t >> 2);

  f32x4 acc[4] = {};
  for (int k0 = 0; k0 < K; k0 += 64) {
    // combine weights for this row x this k-tile's head
    const int hd = k0 >> 6;
    const size_t mi = ((size_t)arow_g * NH + hd) * 2;
    const float m0v = ml0[mi], l0v = ml0[mi + 1];
    const float m1v = ml1[mi], l1v = ml1[mi + 1];
    const float M = fmaxf(m0v, m1v);
    float w0 = __builtin_amdgcn_exp2f(m0v - M);
    float w1 = __builtin_amdgcn_exp2f(m1v - M);
    const float inv = 1.0f / (l0v * w0 + l1v * w1);
    w0 *= inv; w1 *= inv;

    __syncthreads();
    {
      const int row = t >> 2, c0 = (t & 3) * 16;
      const float4* a0 = reinterpret_cast<const float4*>(O0 + (size_t)(m0 + row) * K + k0 + c0);
      const float4* a1 = reinterpret_cast<const float4*>(O1 + (size_t)(m0 + row) * K + k0 + c0);
      #pragma unroll
      for (int j = 0; j < 4; ++j) {
        float4 fa = a0[j], fb = a1[j];
        bf16x4 o = { (bf16_t)(fa.x * w0 + fb.x * w1), (bf16_t)(fa.y * w0 + fb.y * w1),
                     (bf16_t)(fa.z * w0 + fb.z * w1), (bf16_t)(fa.w * w0 + fb.w * w1) };
        *reinterpret_cast<bf16x4*>(&Alds[swz(row, (c0 + j * 4) * 2)]) = o;
      }
    }
    {
      const int row = t >> 2, cb = ((2 * t) & 7) * 16;
      const bf16_t* src = Wt + (size_t)(n0 + row) * K + k0 + cb / 2;
      *reinterpret_cast<bf16x8*>(&Wlds[swz(row, cb)]) = *reinterpret_cast<const bf16x8*>(src);
      *reinterpret_cast<bf16x8*>(&Wlds[swz(row, cb + 16)]) = *reinterpret_cast<const bf16x8*>(src + 8);
    }
    __syncthreads();
    #pragma unroll
    for (int ks = 0; ks < 2; ++ks) {
      const int kb = (ks * 32 + ((l >> 4) * 8)) * 2;
      const int arow = w * 16 + (l & 15);
      bf16x8 af = *reinterpret_cast<const bf16x8*>(&Alds[swz(arow, kb)]);
      #pragma unroll
      for (int ct = 0; ct < 4; ++ct) {
        const int brow = ct * 16 + (l & 15);
        bf16x8 bfr = *reinterpret_cast<const bf16x8*>(&Wlds[swz(brow, kb)]);
        acc[ct] = mfma16(af, bfr, acc[ct]);
      }
    }
  }
  #pragma unroll
  for (int ct = 0; ct < 4; ++ct) {
    const int col = n0 + ct * 16 + (l & 15);
    const float bv = bias[col];
    #pragma unroll
    for (int r = 0; r < 4; ++r) {
      const int row = m0 + w * 16 + ((l >> 4) * 4) + r;
      C[(size_t)row * N + col] = acc[ct][r] + bv;
    }
  }
}

extern "C" void kernel_launch(void* const* d_in, const int* in_sizes, int n_in,
                              void* d_out, int out_size, void* d_ws, size_t ws_size,
                              hipStream_t stream)
{
  const float* query = (const float*)d_in[0];
  const float* keyin = (const float*)d_in[1];
  const int*   mask  = (const int*)d_in[2];
  const float* Wq = (const float*)d_in[3];
  const float* bq = (const float*)d_in[4];
  const float* Wk = (const float*)d_in[5];
  const float* bk = (const float*)d_in[6];
  const float* Wv = (const float*)d_in[7];
  const float* bv = (const float*)d_in[8];
  const float* Wo = (const float*)d_in[9];
  const float* bo = (const float*)d_in[10];
  float* out = (float*)d_out;

  bf16_t* Qp = (bf16_t*)d_ws;
  bf16_t* Kp = Qp + (size_t)MROWS * DMODEL;
  bf16_t* Vt = Kp + (size_t)MROWS * DMODEL;
  bf16_t* AO = Vt + (size_t)MROWS * DMODEL;
  unsigned long long* Mpk = (unsigned long long*)(AO + (size_t)MROWS * DMODEL);
  bf16_t* Wtq = (bf16_t*)(Mpk + MWORDS);
  bf16_t* Wtk = Wtq + 512 * 256;
  bf16_t* Wtv = Wtk + 512 * 256;
  bf16_t* Wto = Wtv + 512 * 256;
  float*  O0  = (float*)(Wto + 512 * 512);
  float*  O1  = O0 + (size_t)MROWS * DMODEL;
  float*  ml0 = O1 + (size_t)MROWS * DMODEL;
  float*  ml1 = ml0 + (size_t)MROWS * NH * 2;
  const size_t need = (size_t)((char*)(ml1 + (size_t)MROWS * NH * 2) - (char*)d_ws);
  const bool split = ws_size >= need;

  dim3 blk(256);

  weight_prep<<<dim3(160), blk, 0, stream>>>(Wq, Wk, Wv, Wo, Wtq, Wtk, Wtv, Wto);
  mask_pack<<<dim3(MWORDS / 256), blk, 0, stream>>>(mask, Mpk);
  gemm_bias_act<256, true, float, bf16_t><<<dim3(1024), blk, 0, stream>>>(query, Wtq, bq, Qp, 1.0f);
  gemm_kv<<<dim3(1024), blk, 0, stream>>>(keyin, Wtk, Wtv, bk, bv, Kp, Vt);

  if (split) {
    attn_split<<<dim3(1024), blk, 0, stream>>>(Qp, Kp, Vt, Mpk, O0, O1, ml0, ml1);
    gemm_out_combine<<<dim3(1024), blk, 0, stream>>>(O0, O1, ml0, ml1, Wto, bo, out);
  } else {
    attn_kernel<<<dim3(NB * NH * (LQ / 128)), blk, 0, stream>>>(Qp, Kp, Vt, Mpk, AO);
    gemm_bias_act<512, false, bf16_t, float><<<dim3(1024), blk, 0, stream>>>(AO, Wto, bo, out, 1.0f);
  }
}

// Round 20
// 106.242 us; speedup vs baseline: 1.1329x; 1.0972x over previous
//
#include <hip/hip_runtime.h>
#include <hip/hip_bf16.h>
#include <type_traits>

typedef __bf16 bf16_t;
typedef __bf16 bf16x4 __attribute__((ext_vector_type(4)));
typedef __bf16 bf16x8 __attribute__((ext_vector_type(8)));
typedef float  f32x4  __attribute__((ext_vector_type(4)));

__device__ __forceinline__ f32x4 mfma16(bf16x8 a, bf16x8 b, f32x4 c) {
  return __builtin_amdgcn_mfma_f32_16x16x32_bf16(a, b, c, 0, 0, 0);
}

static constexpr int NB = 8;
static constexpr int LQ = 1024;
static constexpr int LKk = 1024;
static constexpr int DMODEL = 512;
static constexpr int NH = 8;
static constexpr int DKH = 64;
static constexpr int MROWS = NB * LQ;   // 8192
static constexpr int MWORDS = NB * LQ * (LKk / 64);  // 131072 u64 words
#define KSCALE 0.1803368801111204f

// swizzled byte offset for [R][128B] row-major LDS tiles (G4 XOR swizzle)
__device__ __forceinline__ int swz(int row, int byte) {
  return row * 128 + (byte ^ ((row & 7) << 4));
}

// ------- mask bit-pack: one u64 word per THREAD, 16 independent int4 loads --
__global__ __launch_bounds__(256)
void mask_pack(const int* __restrict__ mask, unsigned long long* __restrict__ mpk) {
  const int wd = blockIdx.x * 256 + threadIdx.x;
  const int4* base = reinterpret_cast<const int4*>(mask + (size_t)wd * 64);
  unsigned long long bits = 0;
  #pragma unroll
  for (int i = 0; i < 16; ++i) {
    int4 v = base[i];
    bits |= (unsigned long long)(v.x != 0) << (4 * i);
    bits |= (unsigned long long)(v.y != 0) << (4 * i + 1);
    bits |= (unsigned long long)(v.z != 0) << (4 * i + 2);
    bits |= (unsigned long long)(v.w != 0) << (4 * i + 3);
  }
  mpk[wd] = bits;
}

// ------- one-time weight transpose+convert: W f32 [K][N] -> Wt bf16 [N][K] --
__device__ __forceinline__ void wt_tile(const float* __restrict__ W, bf16_t* __restrict__ Wt,
                                        int K, int N, int kt, int nt, int t) {
  __shared__ bf16_t T[64][72];
  const int k0 = kt * 64, n0 = nt * 64;
  const int kr = t >> 2, c0 = (t & 3) * 16;
  const float4* src = reinterpret_cast<const float4*>(W + (size_t)(k0 + kr) * N + n0 + c0);
  #pragma unroll
  for (int j = 0; j < 4; ++j) {
    float4 f = src[j];
    T[c0 + j * 4 + 0][kr] = (bf16_t)f.x;
    T[c0 + j * 4 + 1][kr] = (bf16_t)f.y;
    T[c0 + j * 4 + 2][kr] = (bf16_t)f.z;
    T[c0 + j * 4 + 3][kr] = (bf16_t)f.w;
  }
  __syncthreads();
  const int nr = t >> 2, kc0 = (t & 3) * 16;
  bf16_t* dst = Wt + (size_t)(n0 + nr) * K + k0 + kc0;
  #pragma unroll
  for (int j = 0; j < 2; ++j)
    *reinterpret_cast<bf16x8*>(dst + j * 8) =
        *reinterpret_cast<const bf16x8*>(&T[nr][kc0 + j * 8]);
}

__global__ __launch_bounds__(256)
void weight_prep(const float* __restrict__ Wq, const float* __restrict__ Wk,
                 const float* __restrict__ Wv, const float* __restrict__ Wo,
                 bf16_t* __restrict__ Wtq, bf16_t* __restrict__ Wtk,
                 bf16_t* __restrict__ Wtv, bf16_t* __restrict__ Wto) {
  const int bidx = blockIdx.x, t = threadIdx.x;
  if (bidx < 32)        wt_tile(Wq, Wtq, 256, 512, bidx >> 3, bidx & 7, t);
  else if (bidx < 64)   wt_tile(Wk, Wtk, 256, 512, (bidx - 32) >> 3, bidx & 7, t);
  else if (bidx < 96)   wt_tile(Wv, Wtv, 256, 512, (bidx - 64) >> 3, bidx & 7, t);
  else                  wt_tile(Wo, Wto, 512, 512, (bidx - 96) >> 3, bidx & 7, t);
}

// ---- GEMM (R14-proven 64^2 tile, 1024 blocks): C = postscale*act(A@Wt^T+b) --
template<int K, bool RELU, typename AT, typename OT>
__global__ __launch_bounds__(256)
void gemm_bias_act(const AT* __restrict__ A, const bf16_t* __restrict__ Wt,
                   const float* __restrict__ bias, OT* __restrict__ C,
                   float postscale)
{
  constexpr int N = 512;
  __shared__ alignas(16) char Alds[64 * 128];
  __shared__ alignas(16) char Wlds[64 * 128];
  const int t = threadIdx.x;
  const int l = t & 63, w = t >> 6;
  const int xcd = blockIdx.x & 7, idx = blockIdx.x >> 3;
  const int m0 = (xcd * 16 + (idx >> 3)) * 64, n0 = (idx & 7) * 64;

  f32x4 acc[4] = {};
  for (int k0 = 0; k0 < K; k0 += 64) {
    __syncthreads();
    if constexpr (std::is_same<AT, float>::value) {
      const int row = t >> 2, c0 = (t & 3) * 16;
      const float4* ap = reinterpret_cast<const float4*>(A + (size_t)(m0 + row) * K + k0 + c0);
      #pragma unroll
      for (int j = 0; j < 4; ++j) {
        float4 f = ap[j];
        bf16x4 o = { (bf16_t)f.x, (bf16_t)f.y, (bf16_t)f.z, (bf16_t)f.w };
        *reinterpret_cast<bf16x4*>(&Alds[swz(row, (c0 + j * 4) * 2)]) = o;
      }
    } else {
      const int row = t >> 2, cb = ((2 * t) & 7) * 16;
      const bf16_t* src = A + (size_t)(m0 + row) * K + k0 + cb / 2;
      *reinterpret_cast<bf16x8*>(&Alds[swz(row, cb)]) = *reinterpret_cast<const bf16x8*>(src);
      *reinterpret_cast<bf16x8*>(&Alds[swz(row, cb + 16)]) = *reinterpret_cast<const bf16x8*>(src + 8);
    }
    {
      const int row = t >> 2, cb = ((2 * t) & 7) * 16;
      const bf16_t* src = Wt + (size_t)(n0 + row) * K + k0 + cb / 2;
      *reinterpret_cast<bf16x8*>(&Wlds[swz(row, cb)]) = *reinterpret_cast<const bf16x8*>(src);
      *reinterpret_cast<bf16x8*>(&Wlds[swz(row, cb + 16)]) = *reinterpret_cast<const bf16x8*>(src + 8);
    }
    __syncthreads();
    #pragma unroll
    for (int ks = 0; ks < 2; ++ks) {
      const int kb = (ks * 32 + ((l >> 4) * 8)) * 2;
      const int arow = w * 16 + (l & 15);
      bf16x8 af = *reinterpret_cast<const bf16x8*>(&Alds[swz(arow, kb)]);
      #pragma unroll
      for (int ct = 0; ct < 4; ++ct) {
        const int brow = ct * 16 + (l & 15);
        bf16x8 bfr = *reinterpret_cast<const bf16x8*>(&Wlds[swz(brow, kb)]);
        acc[ct] = mfma16(af, bfr, acc[ct]);
      }
    }
  }
  #pragma unroll
  for (int ct = 0; ct < 4; ++ct) {
    const int col = n0 + ct * 16 + (l & 15);
    const float bv = bias[col];
    #pragma unroll
    for (int r = 0; r < 4; ++r) {
      const int row = m0 + w * 16 + ((l >> 4) * 4) + r;
      float x = acc[ct][r] + bv;
      if constexpr (RELU) x = fmaxf(x, 0.f);
      C[(size_t)row * N + col] = (OT)(x * postscale);
    }
  }
}

// ------- merged K+V projection (R14-proven); V written TRANSPOSED -----------
__global__ __launch_bounds__(256)
void gemm_kv(const float* __restrict__ A, const bf16_t* __restrict__ Wtk,
             const bf16_t* __restrict__ Wtv, const float* __restrict__ bk,
             const float* __restrict__ bv, bf16_t* __restrict__ Ck,
             bf16_t* __restrict__ Vt)
{
  constexpr int K = 256, N = 512;
  __shared__ alignas(16) char Alds[64 * 128];
  __shared__ alignas(16) char Wk_lds[64 * 128];
  __shared__ alignas(16) char Wv_lds[64 * 128];
  const int t = threadIdx.x;
  const int l = t & 63, w = t >> 6;
  const int xcd = blockIdx.x & 7, idx = blockIdx.x >> 3;
  const int m0 = (xcd * 16 + (idx >> 3)) * 64, n0 = (idx & 7) * 64;

  f32x4 acck[4] = {}, accv[4] = {};
  for (int k0 = 0; k0 < K; k0 += 64) {
    __syncthreads();
    {
      const int row = t >> 2, c0 = (t & 3) * 16;
      const float4* ap = reinterpret_cast<const float4*>(A + (size_t)(m0 + row) * K + k0 + c0);
      #pragma unroll
      for (int j = 0; j < 4; ++j) {
        float4 f = ap[j];
        bf16x4 o = { (bf16_t)f.x, (bf16_t)f.y, (bf16_t)f.z, (bf16_t)f.w };
        *reinterpret_cast<bf16x4*>(&Alds[swz(row, (c0 + j * 4) * 2)]) = o;
      }
    }
    {
      const int row = t >> 2, cb = ((2 * t) & 7) * 16;
      const bf16_t* sk = Wtk + (size_t)(n0 + row) * K + k0 + cb / 2;
      const bf16_t* sv = Wtv + (size_t)(n0 + row) * K + k0 + cb / 2;
      *reinterpret_cast<bf16x8*>(&Wk_lds[swz(row, cb)]) = *reinterpret_cast<const bf16x8*>(sk);
      *reinterpret_cast<bf16x8*>(&Wk_lds[swz(row, cb + 16)]) = *reinterpret_cast<const bf16x8*>(sk + 8);
      *reinterpret_cast<bf16x8*>(&Wv_lds[swz(row, cb)]) = *reinterpret_cast<const bf16x8*>(sv);
      *reinterpret_cast<bf16x8*>(&Wv_lds[swz(row, cb + 16)]) = *reinterpret_cast<const bf16x8*>(sv + 8);
    }
    __syncthreads();
    #pragma unroll
    for (int ks = 0; ks < 2; ++ks) {
      const int kb = (ks * 32 + ((l >> 4) * 8)) * 2;
      const int arow = w * 16 + (l & 15);
      bf16x8 af = *reinterpret_cast<const bf16x8*>(&Alds[swz(arow, kb)]);
      #pragma unroll
      for (int ct = 0; ct < 4; ++ct) {
        const int brow = ct * 16 + (l & 15);
        bf16x8 bk8 = *reinterpret_cast<const bf16x8*>(&Wk_lds[swz(brow, kb)]);
        bf16x8 bv8 = *reinterpret_cast<const bf16x8*>(&Wv_lds[swz(brow, kb)]);
        acck[ct] = mfma16(af, bk8, acck[ct]);
        accv[ct] = mfma16(af, bv8, accv[ct]);
      }
    }
  }
  const int row0 = m0 + w * 16 + ((l >> 4) * 4);
  const int vb = row0 >> 10;
  const int kv = row0 & 1023;
  #pragma unroll
  for (int ct = 0; ct < 4; ++ct) {
    const int col = n0 + ct * 16 + (l & 15);
    const float bkv = bk[col], bvv = bv[col];
    #pragma unroll
    for (int r = 0; r < 4; ++r)
      Ck[(size_t)(row0 + r) * N + col] = (bf16_t)(fmaxf(acck[ct][r] + bkv, 0.f) * KSCALE);
    bf16x4 vv;
    #pragma unroll
    for (int r = 0; r < 4; ++r) vv[r] = (bf16_t)fmaxf(accv[ct][r] + bvv, 0.f);
    bf16_t* dst = Vt + (((size_t)vb * NH + (col >> 6)) * DKH + (col & 63)) * LKk + kv;
    *reinterpret_cast<bf16x4*>(dst) = vv;
  }
}

// -- flash attention: R14 core scaled to QBLK=64/wave (4 q-groups share every
//    K/V fragment read); bf16x4 P-stores (proven construct). Grid 256.
__global__ __launch_bounds__(256)
void attn_kernel(const bf16_t* __restrict__ Qp, const bf16_t* __restrict__ Kp,
                 const bf16_t* __restrict__ Vt, const unsigned long long* __restrict__ Mpk,
                 bf16_t* __restrict__ AO)
{
  __shared__ alignas(16) char SM[49152];   // K 8K | V 8K | P 4 waves x 8K
  char* Klds = SM;
  char* Vlds = SM + 8192;
  const int t = threadIdx.x, l = t & 63, w = t >> 6;
  const int g = l >> 4, qh = l & 15;
  char* Pw = SM + 16384 + w * 8192;        // per-wave [64 q][64 kv], swizzled
  // grid 256: XCD x = blockIdx.x%8 owns batch x (32 consecutive logical blocks)
  const int bid = (blockIdx.x & 7) * 32 + (blockIdx.x >> 3);
  const int qt = bid & 3, h = (bid >> 2) & 7, b = bid >> 5;
  const int wq0 = qt * 256 + w * 64;       // this wave's 64 q rows (4 groups)
  const size_t rb = (size_t)b * LQ;
  const bf16_t* vtb = Vt + ((size_t)b * NH + h) * DKH * LKk;

  bf16x8 qf[4][2];
  #pragma unroll
  for (int j = 0; j < 4; ++j)
    #pragma unroll
    for (int ks = 0; ks < 2; ++ks)
      qf[j][ks] = *reinterpret_cast<const bf16x8*>(
          Qp + (rb + wq0 + j * 16 + qh) * DMODEL + h * DKH + ks * 32 + g * 8);

  const unsigned long long* mrow = Mpk + (rb + wq0 + qh) * (LKk / 64);

  f32x4 acc[4][4] = {};                    // acc[j][dct][r]
  float mrun[4] = { -1e30f, -1e30f, -1e30f, -1e30f };
  float lsum[4] = {};

  for (int kv0 = 0; kv0 < LKk; kv0 += 64) {
    unsigned long long mw[4];
    #pragma unroll
    for (int j = 0; j < 4; ++j)
      mw[j] = mrow[(size_t)(j * 16) * (LKk / 64) + (kv0 >> 6)];

    __syncthreads();
    // stage K tile [64 kv][64 d] — R9-proven vector pattern
    {
      const int row = t >> 2, cb = ((2 * t) & 7) * 16;
      const bf16_t* src = Kp + (rb + kv0 + row) * DMODEL + h * DKH + cb / 2;
      *reinterpret_cast<bf16x8*>(&Klds[swz(row, cb)]) = *reinterpret_cast<const bf16x8*>(src);
      *reinterpret_cast<bf16x8*>(&Klds[swz(row, cb + 16)]) = *reinterpret_cast<const bf16x8*>(src + 8);
    }
    // stage V tile [64 d][64 kv] from pre-transposed Vt — same pattern
    {
      const int row = t >> 2, cb = ((2 * t) & 7) * 16;
      const bf16_t* src = vtb + (size_t)row * LKk + kv0 + cb / 2;
      *reinterpret_cast<bf16x8*>(&Vlds[swz(row, cb)]) = *reinterpret_cast<const bf16x8*>(src);
      *reinterpret_cast<bf16x8*>(&Vlds[swz(row, cb + 16)]) = *reinterpret_cast<const bf16x8*>(src + 8);
    }
    __syncthreads();

    // S^T = mfma(A=K, B=Q[j]): each K-frag read feeds FOUR q-groups
    f32x4 s[4][4] = {};
    #pragma unroll
    for (int ks = 0; ks < 2; ++ks) {
      const int kb = (ks * 32 + g * 8) * 2;
      #pragma unroll
      for (int ct = 0; ct < 4; ++ct) {
        bf16x8 kf = *reinterpret_cast<const bf16x8*>(&Klds[swz(ct * 16 + qh, kb)]);
        #pragma unroll
        for (int j = 0; j < 4; ++j)
          s[j][ct] = mfma16(kf, qf[j][ks], s[j][ct]);
      }
    }

    // per-group mask + lane-parallel online softmax (exp2 domain)
    #pragma unroll
    for (int j = 0; j < 4; ++j) {
      float rmax = -1e30f;
      #pragma unroll
      for (int ct = 0; ct < 4; ++ct) {
        #pragma unroll
        for (int r = 0; r < 4; ++r) {
          float x = ((mw[j] >> (ct * 16 + g * 4 + r)) & 1) ? s[j][ct][r] : -1e8f;
          s[j][ct][r] = x;
          rmax = fmaxf(rmax, x);
        }
      }
      rmax = fmaxf(rmax, __shfl_xor(rmax, 16));
      rmax = fmaxf(rmax, __shfl_xor(rmax, 32));
      const float newm = fmaxf(mrun[j], rmax);

      if (__any(newm > mrun[j])) {
        const float scale = __builtin_amdgcn_exp2f(mrun[j] - newm);
        lsum[j] *= scale;
        #pragma unroll
        for (int r = 0; r < 4; ++r) {
          const float sr = __shfl(scale, g * 4 + r, 64);
          #pragma unroll
          for (int dct = 0; dct < 4; ++dct) acc[j][dct][r] *= sr;
        }
        mrun[j] = newm;
      }

      float psum = 0.f;
      #pragma unroll
      for (int ct = 0; ct < 4; ++ct) {
        #pragma unroll
        for (int r = 0; r < 4; ++r) {
          const float pv = __builtin_amdgcn_exp2f(s[j][ct][r] - mrun[j]);
          s[j][ct][r] = pv;
          psum += pv;
        }
      }
      psum += __shfl_xor(psum, 16);
      psum += __shfl_xor(psum, 32);
      lsum[j] += psum;

      // P[q=j*16+qh][kv quad] — bf16x4 vector stores (8B, 16B-block-local;
      // same construct as GEMM A-staging, proven since R1)
      #pragma unroll
      for (int ct = 0; ct < 4; ++ct) {
        bf16x4 pk = { (bf16_t)s[j][ct][0], (bf16_t)s[j][ct][1],
                      (bf16_t)s[j][ct][2], (bf16_t)s[j][ct][3] };
        *reinterpret_cast<bf16x4*>(&Pw[swz(j * 16 + qh, (ct * 16 + g * 4) * 2)]) = pk;
      }
    }

    // O += P V: each V-frag read feeds FOUR q-groups
    #pragma unroll
    for (int ks = 0; ks < 2; ++ks) {
      const int kb = (ks * 32 + g * 8) * 2;
      bf16x8 pf[4];
      #pragma unroll
      for (int j = 0; j < 4; ++j)
        pf[j] = *reinterpret_cast<const bf16x8*>(&Pw[swz(j * 16 + qh, kb)]);
      #pragma unroll
      for (int dct = 0; dct < 4; ++dct) {
        bf16x8 vf = *reinterpret_cast<const bf16x8*>(&Vlds[swz(dct * 16 + qh, kb)]);
        #pragma unroll
        for (int j = 0; j < 4; ++j)
          acc[j][dct] = mfma16(pf[j], vf, acc[j][dct]);
      }
    }
  }

  #pragma unroll
  for (int j = 0; j < 4; ++j) {
    const float inv = 1.0f / lsum[j];
    float invr[4];
    #pragma unroll
    for (int r = 0; r < 4; ++r) invr[r] = __shfl(inv, g * 4 + r, 64);
    #pragma unroll
    for (int dct = 0; dct < 4; ++dct) {
      const int col = h * DKH + dct * 16 + qh;
      #pragma unroll
      for (int r = 0; r < 4; ++r) {
        const int q = wq0 + j * 16 + g * 4 + r;
        AO[(rb + q) * DMODEL + col] = (bf16_t)(acc[j][dct][r] * invr[r]);
      }
    }
  }
}

extern "C" void kernel_launch(void* const* d_in, const int* in_sizes, int n_in,
                              void* d_out, int out_size, void* d_ws, size_t ws_size,
                              hipStream_t stream)
{
  const float* query = (const float*)d_in[0];
  const float* keyin = (const float*)d_in[1];
  const int*   mask  = (const int*)d_in[2];
  const float* Wq = (const float*)d_in[3];
  const float* bq = (const float*)d_in[4];
  const float* Wk = (const float*)d_in[5];
  const float* bk = (const float*)d_in[6];
  const float* Wv = (const float*)d_in[7];
  const float* bv = (const float*)d_in[8];
  const float* Wo = (const float*)d_in[9];
  const float* bo = (const float*)d_in[10];
  float* out = (float*)d_out;

  bf16_t* Qp = (bf16_t*)d_ws;
  bf16_t* Kp = Qp + (size_t)MROWS * DMODEL;
  bf16_t* Vt = Kp + (size_t)MROWS * DMODEL;
  bf16_t* AO = Vt + (size_t)MROWS * DMODEL;
  unsigned long long* Mpk = (unsigned long long*)(AO + (size_t)MROWS * DMODEL);
  bf16_t* Wtq = (bf16_t*)(Mpk + MWORDS);
  bf16_t* Wtk = Wtq + 512 * 256;
  bf16_t* Wtv = Wtk + 512 * 256;
  bf16_t* Wto = Wtv + 512 * 256;

  dim3 blk(256);

  weight_prep<<<dim3(160), blk, 0, stream>>>(Wq, Wk, Wv, Wo, Wtq, Wtk, Wtv, Wto);
  mask_pack<<<dim3(MWORDS / 256), blk, 0, stream>>>(mask, Mpk);
  gemm_bias_act<256, true, float, bf16_t><<<dim3(1024), blk, 0, stream>>>(query, Wtq, bq, Qp, 1.0f);
  gemm_kv<<<dim3(1024), blk, 0, stream>>>(keyin, Wtk, Wtv, bk, bv, Kp, Vt);

  attn_kernel<<<dim3(NB * NH * (LQ / 256)), blk, 0, stream>>>(Qp, Kp, Vt, Mpk, AO);

  gemm_bias_act<512, false, bf16_t, float><<<dim3(1024), blk, 0, stream>>>(AO, Wto, bo, out, 1.0f);
}

// Round 21
// 92.293 us; speedup vs baseline: 1.3041x; 1.1511x over previous
//
#include <hip/hip_runtime.h>
#include <hip/hip_bf16.h>
#include <type_traits>

typedef __bf16 bf16_t;
typedef __bf16 bf16x4 __attribute__((ext_vector_type(4)));
typedef __bf16 bf16x8 __attribute__((ext_vector_type(8)));
typedef float  f32x4  __attribute__((ext_vector_type(4)));

__device__ __forceinline__ f32x4 mfma16(bf16x8 a, bf16x8 b, f32x4 c) {
  return __builtin_amdgcn_mfma_f32_16x16x32_bf16(a, b, c, 0, 0, 0);
}

static constexpr int NB = 8;
static constexpr int LQ = 1024;
static constexpr int LKk = 1024;
static constexpr int DMODEL = 512;
static constexpr int NH = 8;
static constexpr int DKH = 64;
static constexpr int MROWS = NB * LQ;   // 8192
static constexpr int MWORDS = NB * LQ * (LKk / 64);  // 131072 u64 words
#define KSCALE 0.1803368801111204f

// swizzled byte offset for [R][128B] row-major LDS tiles (G4 XOR swizzle)
__device__ __forceinline__ int swz(int row, int byte) {
  return row * 128 + (byte ^ ((row & 7) << 4));
}

// ------- one-time weight transpose+convert: W f32 [K][N] -> Wt bf16 [N][K] --
__device__ __forceinline__ void wt_tile(const float* __restrict__ W, bf16_t* __restrict__ Wt,
                                        int K, int N, int kt, int nt, int t) {
  __shared__ bf16_t T[64][72];
  const int k0 = kt * 64, n0 = nt * 64;
  const int kr = t >> 2, c0 = (t & 3) * 16;
  const float4* src = reinterpret_cast<const float4*>(W + (size_t)(k0 + kr) * N + n0 + c0);
  #pragma unroll
  for (int j = 0; j < 4; ++j) {
    float4 f = src[j];
    T[c0 + j * 4 + 0][kr] = (bf16_t)f.x;
    T[c0 + j * 4 + 1][kr] = (bf16_t)f.y;
    T[c0 + j * 4 + 2][kr] = (bf16_t)f.z;
    T[c0 + j * 4 + 3][kr] = (bf16_t)f.w;
  }
  __syncthreads();
  const int nr = t >> 2, kc0 = (t & 3) * 16;
  bf16_t* dst = Wt + (size_t)(n0 + nr) * K + k0 + kc0;
  #pragma unroll
  for (int j = 0; j < 2; ++j)
    *reinterpret_cast<bf16x8*>(dst + j * 8) =
        *reinterpret_cast<const bf16x8*>(&T[nr][kc0 + j * 8]);
}

// ------- fused prep: blocks 0..511 mask_pack | 512..671 weight_prep --------
__global__ __launch_bounds__(256)
void prep_fused(const int* __restrict__ mask, unsigned long long* __restrict__ mpk,
                const float* __restrict__ Wq, const float* __restrict__ Wk,
                const float* __restrict__ Wv, const float* __restrict__ Wo,
                bf16_t* __restrict__ Wtq, bf16_t* __restrict__ Wtk,
                bf16_t* __restrict__ Wtv, bf16_t* __restrict__ Wto) {
  const int bid = blockIdx.x, t = threadIdx.x;
  if (bid < 512) {
    const int wd = bid * 256 + t;
    const int4* base = reinterpret_cast<const int4*>(mask + (size_t)wd * 64);
    unsigned long long bits = 0;
    #pragma unroll
    for (int i = 0; i < 16; ++i) {
      int4 v = base[i];
      bits |= (unsigned long long)(v.x != 0) << (4 * i);
      bits |= (unsigned long long)(v.y != 0) << (4 * i + 1);
      bits |= (unsigned long long)(v.z != 0) << (4 * i + 2);
      bits |= (unsigned long long)(v.w != 0) << (4 * i + 3);
    }
    mpk[wd] = bits;
  } else {
    const int bidx = bid - 512;
    if (bidx < 32)        wt_tile(Wq, Wtq, 256, 512, bidx >> 3, bidx & 7, t);
    else if (bidx < 64)   wt_tile(Wk, Wtk, 256, 512, (bidx - 32) >> 3, bidx & 7, t);
    else if (bidx < 96)   wt_tile(Wv, Wtv, 256, 512, (bidx - 64) >> 3, bidx & 7, t);
    else                  wt_tile(Wo, Wto, 512, 512, (bidx - 96) >> 3, bidx & 7, t);
  }
}

// ---- GEMM (R14-proven 64^2 tile, 1024 blocks): C = postscale*act(A@Wt^T+b) --
template<int K, bool RELU, typename AT, typename OT>
__global__ __launch_bounds__(256)
void gemm_bias_act(const AT* __restrict__ A, const bf16_t* __restrict__ Wt,
                   const float* __restrict__ bias, OT* __restrict__ C,
                   float postscale)
{
  constexpr int N = 512;
  __shared__ alignas(16) char Alds[64 * 128];
  __shared__ alignas(16) char Wlds[64 * 128];
  const int t = threadIdx.x;
  const int l = t & 63, w = t >> 6;
  const int xcd = blockIdx.x & 7, idx = blockIdx.x >> 3;
  const int m0 = (xcd * 16 + (idx >> 3)) * 64, n0 = (idx & 7) * 64;

  f32x4 acc[4] = {};
  for (int k0 = 0; k0 < K; k0 += 64) {
    __syncthreads();
    if constexpr (std::is_same<AT, float>::value) {
      const int row = t >> 2, c0 = (t & 3) * 16;
      const float4* ap = reinterpret_cast<const float4*>(A + (size_t)(m0 + row) * K + k0 + c0);
      #pragma unroll
      for (int j = 0; j < 4; ++j) {
        float4 f = ap[j];
        bf16x4 o = { (bf16_t)f.x, (bf16_t)f.y, (bf16_t)f.z, (bf16_t)f.w };
        *reinterpret_cast<bf16x4*>(&Alds[swz(row, (c0 + j * 4) * 2)]) = o;
      }
    } else {
      const int row = t >> 2, cb = ((2 * t) & 7) * 16;
      const bf16_t* src = A + (size_t)(m0 + row) * K + k0 + cb / 2;
      *reinterpret_cast<bf16x8*>(&Alds[swz(row, cb)]) = *reinterpret_cast<const bf16x8*>(src);
      *reinterpret_cast<bf16x8*>(&Alds[swz(row, cb + 16)]) = *reinterpret_cast<const bf16x8*>(src + 8);
    }
    {
      const int row = t >> 2, cb = ((2 * t) & 7) * 16;
      const bf16_t* src = Wt + (size_t)(n0 + row) * K + k0 + cb / 2;
      *reinterpret_cast<bf16x8*>(&Wlds[swz(row, cb)]) = *reinterpret_cast<const bf16x8*>(src);
      *reinterpret_cast<bf16x8*>(&Wlds[swz(row, cb + 16)]) = *reinterpret_cast<const bf16x8*>(src + 8);
    }
    __syncthreads();
    #pragma unroll
    for (int ks = 0; ks < 2; ++ks) {
      const int kb = (ks * 32 + ((l >> 4) * 8)) * 2;
      const int arow = w * 16 + (l & 15);
      bf16x8 af = *reinterpret_cast<const bf16x8*>(&Alds[swz(arow, kb)]);
      #pragma unroll
      for (int ct = 0; ct < 4; ++ct) {
        const int brow = ct * 16 + (l & 15);
        bf16x8 bfr = *reinterpret_cast<const bf16x8*>(&Wlds[swz(brow, kb)]);
        acc[ct] = mfma16(af, bfr, acc[ct]);
      }
    }
  }
  #pragma unroll
  for (int ct = 0; ct < 4; ++ct) {
    const int col = n0 + ct * 16 + (l & 15);
    const float bv = bias[col];
    #pragma unroll
    for (int r = 0; r < 4; ++r) {
      const int row = m0 + w * 16 + ((l >> 4) * 4) + r;
      float x = acc[ct][r] + bv;
      if constexpr (RELU) x = fmaxf(x, 0.f);
      C[(size_t)row * N + col] = (OT)(x * postscale);
    }
  }
}

// ------- merged K+V projection (R14-proven); V written TRANSPOSED -----------
__global__ __launch_bounds__(256)
void gemm_kv(const float* __restrict__ A, const bf16_t* __restrict__ Wtk,
             const bf16_t* __restrict__ Wtv, const float* __restrict__ bk,
             const float* __restrict__ bv, bf16_t* __restrict__ Ck,
             bf16_t* __restrict__ Vt)
{
  constexpr int K = 256, N = 512;
  __shared__ alignas(16) char Alds[64 * 128];
  __shared__ alignas(16) char Wk_lds[64 * 128];
  __shared__ alignas(16) char Wv_lds[64 * 128];
  const int t = threadIdx.x;
  const int l = t & 63, w = t >> 6;
  const int xcd = blockIdx.x & 7, idx = blockIdx.x >> 3;
  const int m0 = (xcd * 16 + (idx >> 3)) * 64, n0 = (idx & 7) * 64;

  f32x4 acck[4] = {}, accv[4] = {};
  for (int k0 = 0; k0 < K; k0 += 64) {
    __syncthreads();
    {
      const int row = t >> 2, c0 = (t & 3) * 16;
      const float4* ap = reinterpret_cast<const float4*>(A + (size_t)(m0 + row) * K + k0 + c0);
      #pragma unroll
      for (int j = 0; j < 4; ++j) {
        float4 f = ap[j];
        bf16x4 o = { (bf16_t)f.x, (bf16_t)f.y, (bf16_t)f.z, (bf16_t)f.w };
        *reinterpret_cast<bf16x4*>(&Alds[swz(row, (c0 + j * 4) * 2)]) = o;
      }
    }
    {
      const int row = t >> 2, cb = ((2 * t) & 7) * 16;
      const bf16_t* sk = Wtk + (size_t)(n0 + row) * K + k0 + cb / 2;
      const bf16_t* sv = Wtv + (size_t)(n0 + row) * K + k0 + cb / 2;
      *reinterpret_cast<bf16x8*>(&Wk_lds[swz(row, cb)]) = *reinterpret_cast<const bf16x8*>(sk);
      *reinterpret_cast<bf16x8*>(&Wk_lds[swz(row, cb + 16)]) = *reinterpret_cast<const bf16x8*>(sk + 8);
      *reinterpret_cast<bf16x8*>(&Wv_lds[swz(row, cb)]) = *reinterpret_cast<const bf16x8*>(sv);
      *reinterpret_cast<bf16x8*>(&Wv_lds[swz(row, cb + 16)]) = *reinterpret_cast<const bf16x8*>(sv + 8);
    }
    __syncthreads();
    #pragma unroll
    for (int ks = 0; ks < 2; ++ks) {
      const int kb = (ks * 32 + ((l >> 4) * 8)) * 2;
      const int arow = w * 16 + (l & 15);
      bf16x8 af = *reinterpret_cast<const bf16x8*>(&Alds[swz(arow, kb)]);
      #pragma unroll
      for (int ct = 0; ct < 4; ++ct) {
        const int brow = ct * 16 + (l & 15);
        bf16x8 bk8 = *reinterpret_cast<const bf16x8*>(&Wk_lds[swz(brow, kb)]);
        bf16x8 bv8 = *reinterpret_cast<const bf16x8*>(&Wv_lds[swz(brow, kb)]);
        acck[ct] = mfma16(af, bk8, acck[ct]);
        accv[ct] = mfma16(af, bv8, accv[ct]);
      }
    }
  }
  const int row0 = m0 + w * 16 + ((l >> 4) * 4);
  const int vb = row0 >> 10;
  const int kv = row0 & 1023;
  #pragma unroll
  for (int ct = 0; ct < 4; ++ct) {
    const int col = n0 + ct * 16 + (l & 15);
    const float bkv = bk[col], bvv = bv[col];
    #pragma unroll
    for (int r = 0; r < 4; ++r)
      Ck[(size_t)(row0 + r) * N + col] = (bf16_t)(fmaxf(acck[ct][r] + bkv, 0.f) * KSCALE);
    bf16x4 vv;
    #pragma unroll
    for (int r = 0; r < 4; ++r) vv[r] = (bf16_t)fmaxf(accv[ct][r] + bvv, 0.f);
    bf16_t* dst = Vt + (((size_t)vb * NH + (col >> 6)) * DKH + (col & 63)) * LKk + kv;
    *reinterpret_cast<bf16x4*>(dst) = vv;
  }
}

// -- flash attention: R14 core (QBLK=32, 4 waves, 512 blocks) with
//    KVBLK=128 double-tile staging (half the barriers). Per-tile compute
//    byte-identical to R14.
__global__ __launch_bounds__(256)
void attn_kernel(const bf16_t* __restrict__ Qp, const bf16_t* __restrict__ Kp,
                 const bf16_t* __restrict__ Vt, const unsigned long long* __restrict__ Mpk,
                 bf16_t* __restrict__ AO)
{
  __shared__ alignas(16) char K1[8192], K2[8192], V1[8192], V2[8192];
  __shared__ alignas(16) char Plds[4 * 32 * 128];
  const int t = threadIdx.x, l = t & 63, w = t >> 6;
  const int g = l >> 4, qh = l & 15;
  const int bid = (blockIdx.x & 7) * 64 + (blockIdx.x >> 3);
  const int qt = bid & 7, h = (bid >> 3) & 7, b = bid >> 6;
  const int wq0 = qt * 128 + w * 32;
  const size_t rb = (size_t)b * LQ;
  const bf16_t* vtb = Vt + ((size_t)b * NH + h) * DKH * LKk;

  bf16x8 qf[2][2];
  #pragma unroll
  for (int j = 0; j < 2; ++j)
    #pragma unroll
    for (int ks = 0; ks < 2; ++ks)
      qf[j][ks] = *reinterpret_cast<const bf16x8*>(
          Qp + (rb + wq0 + j * 16 + qh) * DMODEL + h * DKH + ks * 32 + g * 8);

  const unsigned long long* mrow0 = Mpk + (rb + wq0 + qh) * (LKk / 64);
  const unsigned long long* mrow1 = Mpk + (rb + wq0 + 16 + qh) * (LKk / 64);

  f32x4 acc[2][4] = {};
  float mrun[2] = { -1e30f, -1e30f }, lsum[2] = { 0.f, 0.f };

  const int srow = t >> 2, scb = ((2 * t) & 7) * 16;

  for (int kv0 = 0; kv0 < LKk; kv0 += 128) {
    __syncthreads();
    // stage TWO 64-kv tiles of K and V (R9-proven vector pattern x2)
    {
      const bf16_t* sk1 = Kp + (rb + kv0 + srow) * DMODEL + h * DKH + scb / 2;
      const bf16_t* sk2 = sk1 + (size_t)64 * DMODEL;
      *reinterpret_cast<bf16x8*>(&K1[swz(srow, scb)]) = *reinterpret_cast<const bf16x8*>(sk1);
      *reinterpret_cast<bf16x8*>(&K1[swz(srow, scb + 16)]) = *reinterpret_cast<const bf16x8*>(sk1 + 8);
      *reinterpret_cast<bf16x8*>(&K2[swz(srow, scb)]) = *reinterpret_cast<const bf16x8*>(sk2);
      *reinterpret_cast<bf16x8*>(&K2[swz(srow, scb + 16)]) = *reinterpret_cast<const bf16x8*>(sk2 + 8);
      const bf16_t* sv1 = vtb + (size_t)srow * LKk + kv0 + scb / 2;
      const bf16_t* sv2 = sv1 + 64;
      *reinterpret_cast<bf16x8*>(&V1[swz(srow, scb)]) = *reinterpret_cast<const bf16x8*>(sv1);
      *reinterpret_cast<bf16x8*>(&V1[swz(srow, scb + 16)]) = *reinterpret_cast<const bf16x8*>(sv1 + 8);
      *reinterpret_cast<bf16x8*>(&V2[swz(srow, scb)]) = *reinterpret_cast<const bf16x8*>(sv2);
      *reinterpret_cast<bf16x8*>(&V2[swz(srow, scb + 16)]) = *reinterpret_cast<const bf16x8*>(sv2 + 8);
    }
    __syncthreads();

    #pragma unroll
    for (int half = 0; half < 2; ++half) {
      const char* Klds = half ? K2 : K1;
      const char* Vlds = half ? V2 : V1;
      const int kvh = (kv0 >> 6) + half;
      const unsigned long long mw[2] = { mrow0[kvh], mrow1[kvh] };

      f32x4 s[2][4] = {};
      #pragma unroll
      for (int ks = 0; ks < 2; ++ks) {
        const int kb = (ks * 32 + g * 8) * 2;
        #pragma unroll
        for (int ct = 0; ct < 4; ++ct) {
          bf16x8 kf = *reinterpret_cast<const bf16x8*>(&Klds[swz(ct * 16 + qh, kb)]);
          s[0][ct] = mfma16(kf, qf[0][ks], s[0][ct]);
          s[1][ct] = mfma16(kf, qf[1][ks], s[1][ct]);
        }
      }

      #pragma unroll
      for (int j = 0; j < 2; ++j) {
        float rmax = -1e30f;
        #pragma unroll
        for (int ct = 0; ct < 4; ++ct) {
          #pragma unroll
          for (int r = 0; r < 4; ++r) {
            float x = ((mw[j] >> (ct * 16 + g * 4 + r)) & 1) ? s[j][ct][r] : -1e8f;
            s[j][ct][r] = x;
            rmax = fmaxf(rmax, x);
          }
        }
        rmax = fmaxf(rmax, __shfl_xor(rmax, 16));
        rmax = fmaxf(rmax, __shfl_xor(rmax, 32));
        const float newm = fmaxf(mrun[j], rmax);

        if (__any(newm > mrun[j])) {
          const float scale = __builtin_amdgcn_exp2f(mrun[j] - newm);
          lsum[j] *= scale;
          #pragma unroll
          for (int r = 0; r < 4; ++r) {
            const float sr = __shfl(scale, g * 4 + r, 64);
            #pragma unroll
            for (int dct = 0; dct < 4; ++dct) acc[j][dct][r] *= sr;
          }
          mrun[j] = newm;
        }

        float psum = 0.f;
        #pragma unroll
        for (int ct = 0; ct < 4; ++ct) {
          #pragma unroll
          for (int r = 0; r < 4; ++r) {
            const float pv = __builtin_amdgcn_exp2f(s[j][ct][r] - mrun[j]);
            s[j][ct][r] = pv;
            psum += pv;
          }
        }
        psum += __shfl_xor(psum, 16);
        psum += __shfl_xor(psum, 32);
        lsum[j] += psum;

        // P writes — SCALAR bf16 stores (R14-proven; curse rule)
        #pragma unroll
        for (int ct = 0; ct < 4; ++ct) {
          #pragma unroll
          for (int r = 0; r < 4; ++r)
            *reinterpret_cast<bf16_t*>(
                &Plds[w * 4096 + swz(j * 16 + qh, (ct * 16 + g * 4 + r) * 2)]) =
                (bf16_t)s[j][ct][r];
        }
      }

      #pragma unroll
      for (int ks = 0; ks < 2; ++ks) {
        const int kb = (ks * 32 + g * 8) * 2;
        bf16x8 pf0 = *reinterpret_cast<const bf16x8*>(&Plds[w * 4096 + swz(qh, kb)]);
        bf16x8 pf1 = *reinterpret_cast<const bf16x8*>(&Plds[w * 4096 + swz(16 + qh, kb)]);
        #pragma unroll
        for (int dct = 0; dct < 4; ++dct) {
          bf16x8 vf = *reinterpret_cast<const bf16x8*>(&Vlds[swz(dct * 16 + qh, kb)]);
          acc[0][dct] = mfma16(pf0, vf, acc[0][dct]);
          acc[1][dct] = mfma16(pf1, vf, acc[1][dct]);
        }
      }
    }
  }

  #pragma unroll
  for (int j = 0; j < 2; ++j) {
    const float inv = 1.0f / lsum[j];
    float invr[4];
    #pragma unroll
    for (int r = 0; r < 4; ++r) invr[r] = __shfl(inv, g * 4 + r, 64);
    #pragma unroll
    for (int dct = 0; dct < 4; ++dct) {
      const int col = h * DKH + dct * 16 + qh;
      #pragma unroll
      for (int r = 0; r < 4; ++r) {
        const int q = wq0 + j * 16 + g * 4 + r;
        AO[(rb + q) * DMODEL + col] = (bf16_t)(acc[j][dct][r] * invr[r]);
      }
    }
  }
}

extern "C" void kernel_launch(void* const* d_in, const int* in_sizes, int n_in,
                              void* d_out, int out_size, void* d_ws, size_t ws_size,
                              hipStream_t stream)
{
  const float* query = (const float*)d_in[0];
  const float* keyin = (const float*)d_in[1];
  const int*   mask  = (const int*)d_in[2];
  const float* Wq = (const float*)d_in[3];
  const float* bq = (const float*)d_in[4];
  const float* Wk = (const float*)d_in[5];
  const float* bk = (const float*)d_in[6];
  const float* Wv = (const float*)d_in[7];
  const float* bv = (const float*)d_in[8];
  const float* Wo = (const float*)d_in[9];
  const float* bo = (const float*)d_in[10];
  float* out = (float*)d_out;

  bf16_t* Qp = (bf16_t*)d_ws;
  bf16_t* Kp = Qp + (size_t)MROWS * DMODEL;
  bf16_t* Vt = Kp + (size_t)MROWS * DMODEL;
  bf16_t* AO = Vt + (size_t)MROWS * DMODEL;
  unsigned long long* Mpk = (unsigned long long*)(AO + (size_t)MROWS * DMODEL);
  bf16_t* Wtq = (bf16_t*)(Mpk + MWORDS);
  bf16_t* Wtk = Wtq + 512 * 256;
  bf16_t* Wtv = Wtk + 512 * 256;
  bf16_t* Wto = Wtv + 512 * 256;

  dim3 blk(256);

  prep_fused<<<dim3(672), blk, 0, stream>>>(mask, Mpk, Wq, Wk, Wv, Wo, Wtq, Wtk, Wtv, Wto);
  gemm_bias_act<256, true, float, bf16_t><<<dim3(1024), blk, 0, stream>>>(query, Wtq, bq, Qp, 1.0f);
  gemm_kv<<<dim3(1024), blk, 0, stream>>>(keyin, Wtk, Wtv, bk, bv, Kp, Vt);

  attn_kernel<<<dim3(NB * NH * (LQ / 128)), blk, 0, stream>>>(Qp, Kp, Vt, Mpk, AO);

  gemm_bias_act<512, false, bf16_t, float><<<dim3(1024), blk, 0, stream>>>(AO, Wto, bo, out, 1.0f);
}

// Round 22
// 92.113 us; speedup vs baseline: 1.3066x; 1.0020x over previous
//
#include <hip/hip_runtime.h>
#include <hip/hip_bf16.h>
#include <type_traits>

typedef __bf16 bf16_t;
typedef __bf16 bf16x4 __attribute__((ext_vector_type(4)));
typedef __bf16 bf16x8 __attribute__((ext_vector_type(8)));
typedef float  f32x4  __attribute__((ext_vector_type(4)));

__device__ __forceinline__ f32x4 mfma16(bf16x8 a, bf16x8 b, f32x4 c) {
  return __builtin_amdgcn_mfma_f32_16x16x32_bf16(a, b, c, 0, 0, 0);
}

static constexpr int NB = 8;
static constexpr int LQ = 1024;
static constexpr int LKk = 1024;
static constexpr int DMODEL = 512;
static constexpr int NH = 8;
static constexpr int DKH = 64;
static constexpr int MROWS = NB * LQ;   // 8192
static constexpr int MWORDS = NB * LQ * (LKk / 64);  // 131072 u64 words
#define KSCALE 0.1803368801111204f

// swizzled byte offset for [R][128B] row-major LDS tiles (G4 XOR swizzle)
__device__ __forceinline__ int swz(int row, int byte) {
  return row * 128 + (byte ^ ((row & 7) << 4));
}

// ------- one-time weight transpose+convert: W f32 [K][N] -> Wt bf16 [N][K] --
__device__ __forceinline__ void wt_tile(const float* __restrict__ W, bf16_t* __restrict__ Wt,
                                        int K, int N, int kt, int nt, int t) {
  __shared__ bf16_t T[64][72];
  const int k0 = kt * 64, n0 = nt * 64;
  const int kr = t >> 2, c0 = (t & 3) * 16;
  const float4* src = reinterpret_cast<const float4*>(W + (size_t)(k0 + kr) * N + n0 + c0);
  #pragma unroll
  for (int j = 0; j < 4; ++j) {
    float4 f = src[j];
    T[c0 + j * 4 + 0][kr] = (bf16_t)f.x;
    T[c0 + j * 4 + 1][kr] = (bf16_t)f.y;
    T[c0 + j * 4 + 2][kr] = (bf16_t)f.z;
    T[c0 + j * 4 + 3][kr] = (bf16_t)f.w;
  }
  __syncthreads();
  const int nr = t >> 2, kc0 = (t & 3) * 16;
  bf16_t* dst = Wt + (size_t)(n0 + nr) * K + k0 + kc0;
  #pragma unroll
  for (int j = 0; j < 2; ++j)
    *reinterpret_cast<bf16x8*>(dst + j * 8) =
        *reinterpret_cast<const bf16x8*>(&T[nr][kc0 + j * 8]);
}

// ------- fused prep: blocks 0..511 mask_pack | 512..671 weight_prep --------
__global__ __launch_bounds__(256)
void prep_fused(const int* __restrict__ mask, unsigned long long* __restrict__ mpk,
                const float* __restrict__ Wq, const float* __restrict__ Wk,
                const float* __restrict__ Wv, const float* __restrict__ Wo,
                bf16_t* __restrict__ Wtq, bf16_t* __restrict__ Wtk,
                bf16_t* __restrict__ Wtv, bf16_t* __restrict__ Wto) {
  const int bid = blockIdx.x, t = threadIdx.x;
  if (bid < 512) {
    const int wd = bid * 256 + t;
    const int4* base = reinterpret_cast<const int4*>(mask + (size_t)wd * 64);
    unsigned long long bits = 0;
    #pragma unroll
    for (int i = 0; i < 16; ++i) {
      int4 v = base[i];
      bits |= (unsigned long long)(v.x != 0) << (4 * i);
      bits |= (unsigned long long)(v.y != 0) << (4 * i + 1);
      bits |= (unsigned long long)(v.z != 0) << (4 * i + 2);
      bits |= (unsigned long long)(v.w != 0) << (4 * i + 3);
    }
    mpk[wd] = bits;
  } else {
    const int bidx = bid - 512;
    if (bidx < 32)        wt_tile(Wq, Wtq, 256, 512, bidx >> 3, bidx & 7, t);
    else if (bidx < 64)   wt_tile(Wk, Wtk, 256, 512, (bidx - 32) >> 3, bidx & 7, t);
    else if (bidx < 96)   wt_tile(Wv, Wtv, 256, 512, (bidx - 64) >> 3, bidx & 7, t);
    else                  wt_tile(Wo, Wto, 512, 512, (bidx - 96) >> 3, bidx & 7, t);
  }
}

// ---- GEMM (R14-proven 64^2 tile, 1024 blocks): C = postscale*act(A@Wt^T+b) --
template<int K, bool RELU, typename AT, typename OT>
__global__ __launch_bounds__(256)
void gemm_bias_act(const AT* __restrict__ A, const bf16_t* __restrict__ Wt,
                   const float* __restrict__ bias, OT* __restrict__ C,
                   float postscale)
{
  constexpr int N = 512;
  __shared__ alignas(16) char Alds[64 * 128];
  __shared__ alignas(16) char Wlds[64 * 128];
  const int t = threadIdx.x;
  const int l = t & 63, w = t >> 6;
  const int xcd = blockIdx.x & 7, idx = blockIdx.x >> 3;
  const int m0 = (xcd * 16 + (idx >> 3)) * 64, n0 = (idx & 7) * 64;

  f32x4 acc[4] = {};
  for (int k0 = 0; k0 < K; k0 += 64) {
    __syncthreads();
    if constexpr (std::is_same<AT, float>::value) {
      const int row = t >> 2, c0 = (t & 3) * 16;
      const float4* ap = reinterpret_cast<const float4*>(A + (size_t)(m0 + row) * K + k0 + c0);
      #pragma unroll
      for (int j = 0; j < 4; ++j) {
        float4 f = ap[j];
        bf16x4 o = { (bf16_t)f.x, (bf16_t)f.y, (bf16_t)f.z, (bf16_t)f.w };
        *reinterpret_cast<bf16x4*>(&Alds[swz(row, (c0 + j * 4) * 2)]) = o;
      }
    } else {
      const int row = t >> 2, cb = ((2 * t) & 7) * 16;
      const bf16_t* src = A + (size_t)(m0 + row) * K + k0 + cb / 2;
      *reinterpret_cast<bf16x8*>(&Alds[swz(row, cb)]) = *reinterpret_cast<const bf16x8*>(src);
      *reinterpret_cast<bf16x8*>(&Alds[swz(row, cb + 16)]) = *reinterpret_cast<const bf16x8*>(src + 8);
    }
    {
      const int row = t >> 2, cb = ((2 * t) & 7) * 16;
      const bf16_t* src = Wt + (size_t)(n0 + row) * K + k0 + cb / 2;
      *reinterpret_cast<bf16x8*>(&Wlds[swz(row, cb)]) = *reinterpret_cast<const bf16x8*>(src);
      *reinterpret_cast<bf16x8*>(&Wlds[swz(row, cb + 16)]) = *reinterpret_cast<const bf16x8*>(src + 8);
    }
    __syncthreads();
    #pragma unroll
    for (int ks = 0; ks < 2; ++ks) {
      const int kb = (ks * 32 + ((l >> 4) * 8)) * 2;
      const int arow = w * 16 + (l & 15);
      bf16x8 af = *reinterpret_cast<const bf16x8*>(&Alds[swz(arow, kb)]);
      #pragma unroll
      for (int ct = 0; ct < 4; ++ct) {
        const int brow = ct * 16 + (l & 15);
        bf16x8 bfr = *reinterpret_cast<const bf16x8*>(&Wlds[swz(brow, kb)]);
        acc[ct] = mfma16(af, bfr, acc[ct]);
      }
    }
  }
  #pragma unroll
  for (int ct = 0; ct < 4; ++ct) {
    const int col = n0 + ct * 16 + (l & 15);
    const float bv = bias[col];
    #pragma unroll
    for (int r = 0; r < 4; ++r) {
      const int row = m0 + w * 16 + ((l >> 4) * 4) + r;
      float x = acc[ct][r] + bv;
      if constexpr (RELU) x = fmaxf(x, 0.f);
      C[(size_t)row * N + col] = (OT)(x * postscale);
    }
  }
}

// ------- fused QKV projection: blocks 0..1023 Q-proj | 1024..2047 K+V -------
__global__ __launch_bounds__(256)
void gemm_qkv(const float* __restrict__ query, const float* __restrict__ keyin,
              const bf16_t* __restrict__ Wtq, const bf16_t* __restrict__ Wtk,
              const bf16_t* __restrict__ Wtv, const float* __restrict__ bq,
              const float* __restrict__ bk, const float* __restrict__ bv,
              bf16_t* __restrict__ Qp, bf16_t* __restrict__ Ck,
              bf16_t* __restrict__ Vt)
{
  constexpr int K = 256, N = 512;
  __shared__ alignas(16) char Alds[64 * 128];
  __shared__ alignas(16) char W1_lds[64 * 128];
  __shared__ alignas(16) char W2_lds[64 * 128];
  const int t = threadIdx.x;
  const int l = t & 63, w = t >> 6;
  const bool isQ = blockIdx.x < 1024;
  const int lb = isQ ? blockIdx.x : blockIdx.x - 1024;
  const int xcd = lb & 7, idx = lb >> 3;
  const int m0 = (xcd * 16 + (idx >> 3)) * 64, n0 = (idx & 7) * 64;
  const float* A = isQ ? query : keyin;

  f32x4 acc1[4] = {}, acc2[4] = {};
  for (int k0 = 0; k0 < K; k0 += 64) {
    __syncthreads();
    {
      const int row = t >> 2, c0 = (t & 3) * 16;
      const float4* ap = reinterpret_cast<const float4*>(A + (size_t)(m0 + row) * K + k0 + c0);
      #pragma unroll
      for (int j = 0; j < 4; ++j) {
        float4 f = ap[j];
        bf16x4 o = { (bf16_t)f.x, (bf16_t)f.y, (bf16_t)f.z, (bf16_t)f.w };
        *reinterpret_cast<bf16x4*>(&Alds[swz(row, (c0 + j * 4) * 2)]) = o;
      }
    }
    {
      const int row = t >> 2, cb = ((2 * t) & 7) * 16;
      const bf16_t* s1 = (isQ ? Wtq : Wtk) + (size_t)(n0 + row) * K + k0 + cb / 2;
      *reinterpret_cast<bf16x8*>(&W1_lds[swz(row, cb)]) = *reinterpret_cast<const bf16x8*>(s1);
      *reinterpret_cast<bf16x8*>(&W1_lds[swz(row, cb + 16)]) = *reinterpret_cast<const bf16x8*>(s1 + 8);
      if (!isQ) {
        const bf16_t* s2 = Wtv + (size_t)(n0 + row) * K + k0 + cb / 2;
        *reinterpret_cast<bf16x8*>(&W2_lds[swz(row, cb)]) = *reinterpret_cast<const bf16x8*>(s2);
        *reinterpret_cast<bf16x8*>(&W2_lds[swz(row, cb + 16)]) = *reinterpret_cast<const bf16x8*>(s2 + 8);
      }
    }
    __syncthreads();
    #pragma unroll
    for (int ks = 0; ks < 2; ++ks) {
      const int kb = (ks * 32 + ((l >> 4) * 8)) * 2;
      const int arow = w * 16 + (l & 15);
      bf16x8 af = *reinterpret_cast<const bf16x8*>(&Alds[swz(arow, kb)]);
      #pragma unroll
      for (int ct = 0; ct < 4; ++ct) {
        const int brow = ct * 16 + (l & 15);
        bf16x8 b1 = *reinterpret_cast<const bf16x8*>(&W1_lds[swz(brow, kb)]);
        acc1[ct] = mfma16(af, b1, acc1[ct]);
        if (!isQ) {
          bf16x8 b2 = *reinterpret_cast<const bf16x8*>(&W2_lds[swz(brow, kb)]);
          acc2[ct] = mfma16(af, b2, acc2[ct]);
        }
      }
    }
  }
  if (isQ) {
    #pragma unroll
    for (int ct = 0; ct < 4; ++ct) {
      const int col = n0 + ct * 16 + (l & 15);
      const float bb = bq[col];
      #pragma unroll
      for (int r = 0; r < 4; ++r) {
        const int row = m0 + w * 16 + ((l >> 4) * 4) + r;
        Qp[(size_t)row * N + col] = (bf16_t)fmaxf(acc1[ct][r] + bb, 0.f);
      }
    }
  } else {
    const int row0 = m0 + w * 16 + ((l >> 4) * 4);
    const int vb = row0 >> 10;
    const int kv = row0 & 1023;
    #pragma unroll
    for (int ct = 0; ct < 4; ++ct) {
      const int col = n0 + ct * 16 + (l & 15);
      const float bkv = bk[col], bvv = bv[col];
      #pragma unroll
      for (int r = 0; r < 4; ++r)
        Ck[(size_t)(row0 + r) * N + col] = (bf16_t)(fmaxf(acc1[ct][r] + bkv, 0.f) * KSCALE);
      bf16x4 vv;
      #pragma unroll
      for (int r = 0; r < 4; ++r) vv[r] = (bf16_t)fmaxf(acc2[ct][r] + bvv, 0.f);
      bf16_t* dst = Vt + (((size_t)vb * NH + (col >> 6)) * DKH + (col & 63)) * LKk + kv;
      *reinterpret_cast<bf16x4*>(dst) = vv;
    }
  }
}

// -- flash attention: R21 (KVBLK=128, QBLK=32, 4 waves) + bf16x4 P-stores
//    (construct proven correct by R20's passing run)
__global__ __launch_bounds__(256)
void attn_kernel(const bf16_t* __restrict__ Qp, const bf16_t* __restrict__ Kp,
                 const bf16_t* __restrict__ Vt, const unsigned long long* __restrict__ Mpk,
                 bf16_t* __restrict__ AO)
{
  __shared__ alignas(16) char K1[8192], K2[8192], V1[8192], V2[8192];
  __shared__ alignas(16) char Plds[4 * 32 * 128];
  const int t = threadIdx.x, l = t & 63, w = t >> 6;
  const int g = l >> 4, qh = l & 15;
  const int bid = (blockIdx.x & 7) * 64 + (blockIdx.x >> 3);
  const int qt = bid & 7, h = (bid >> 3) & 7, b = bid >> 6;
  const int wq0 = qt * 128 + w * 32;
  const size_t rb = (size_t)b * LQ;
  const bf16_t* vtb = Vt + ((size_t)b * NH + h) * DKH * LKk;

  bf16x8 qf[2][2];
  #pragma unroll
  for (int j = 0; j < 2; ++j)
    #pragma unroll
    for (int ks = 0; ks < 2; ++ks)
      qf[j][ks] = *reinterpret_cast<const bf16x8*>(
          Qp + (rb + wq0 + j * 16 + qh) * DMODEL + h * DKH + ks * 32 + g * 8);

  const unsigned long long* mrow0 = Mpk + (rb + wq0 + qh) * (LKk / 64);
  const unsigned long long* mrow1 = Mpk + (rb + wq0 + 16 + qh) * (LKk / 64);

  f32x4 acc[2][4] = {};
  float mrun[2] = { -1e30f, -1e30f }, lsum[2] = { 0.f, 0.f };

  const int srow = t >> 2, scb = ((2 * t) & 7) * 16;

  for (int kv0 = 0; kv0 < LKk; kv0 += 128) {
    __syncthreads();
    {
      const bf16_t* sk1 = Kp + (rb + kv0 + srow) * DMODEL + h * DKH + scb / 2;
      const bf16_t* sk2 = sk1 + (size_t)64 * DMODEL;
      *reinterpret_cast<bf16x8*>(&K1[swz(srow, scb)]) = *reinterpret_cast<const bf16x8*>(sk1);
      *reinterpret_cast<bf16x8*>(&K1[swz(srow, scb + 16)]) = *reinterpret_cast<const bf16x8*>(sk1 + 8);
      *reinterpret_cast<bf16x8*>(&K2[swz(srow, scb)]) = *reinterpret_cast<const bf16x8*>(sk2);
      *reinterpret_cast<bf16x8*>(&K2[swz(srow, scb + 16)]) = *reinterpret_cast<const bf16x8*>(sk2 + 8);
      const bf16_t* sv1 = vtb + (size_t)srow * LKk + kv0 + scb / 2;
      const bf16_t* sv2 = sv1 + 64;
      *reinterpret_cast<bf16x8*>(&V1[swz(srow, scb)]) = *reinterpret_cast<const bf16x8*>(sv1);
      *reinterpret_cast<bf16x8*>(&V1[swz(srow, scb + 16)]) = *reinterpret_cast<const bf16x8*>(sv1 + 8);
      *reinterpret_cast<bf16x8*>(&V2[swz(srow, scb)]) = *reinterpret_cast<const bf16x8*>(sv2);
      *reinterpret_cast<bf16x8*>(&V2[swz(srow, scb + 16)]) = *reinterpret_cast<const bf16x8*>(sv2 + 8);
    }
    __syncthreads();

    #pragma unroll
    for (int half = 0; half < 2; ++half) {
      const char* Klds = half ? K2 : K1;
      const char* Vlds = half ? V2 : V1;
      const int kvh = (kv0 >> 6) + half;
      const unsigned long long mw[2] = { mrow0[kvh], mrow1[kvh] };

      f32x4 s[2][4] = {};
      #pragma unroll
      for (int ks = 0; ks < 2; ++ks) {
        const int kb = (ks * 32 + g * 8) * 2;
        #pragma unroll
        for (int ct = 0; ct < 4; ++ct) {
          bf16x8 kf = *reinterpret_cast<const bf16x8*>(&Klds[swz(ct * 16 + qh, kb)]);
          s[0][ct] = mfma16(kf, qf[0][ks], s[0][ct]);
          s[1][ct] = mfma16(kf, qf[1][ks], s[1][ct]);
        }
      }

      #pragma unroll
      for (int j = 0; j < 2; ++j) {
        float rmax = -1e30f;
        #pragma unroll
        for (int ct = 0; ct < 4; ++ct) {
          #pragma unroll
          for (int r = 0; r < 4; ++r) {
            float x = ((mw[j] >> (ct * 16 + g * 4 + r)) & 1) ? s[j][ct][r] : -1e8f;
            s[j][ct][r] = x;
            rmax = fmaxf(rmax, x);
          }
        }
        rmax = fmaxf(rmax, __shfl_xor(rmax, 16));
        rmax = fmaxf(rmax, __shfl_xor(rmax, 32));
        const float newm = fmaxf(mrun[j], rmax);

        if (__any(newm > mrun[j])) {
          const float scale = __builtin_amdgcn_exp2f(mrun[j] - newm);
          lsum[j] *= scale;
          #pragma unroll
          for (int r = 0; r < 4; ++r) {
            const float sr = __shfl(scale, g * 4 + r, 64);
            #pragma unroll
            for (int dct = 0; dct < 4; ++dct) acc[j][dct][r] *= sr;
          }
          mrun[j] = newm;
        }

        float psum = 0.f;
        #pragma unroll
        for (int ct = 0; ct < 4; ++ct) {
          #pragma unroll
          for (int r = 0; r < 4; ++r) {
            const float pv = __builtin_amdgcn_exp2f(s[j][ct][r] - mrun[j]);
            s[j][ct][r] = pv;
            psum += pv;
          }
        }
        psum += __shfl_xor(psum, 16);
        psum += __shfl_xor(psum, 32);
        lsum[j] += psum;

        // P stores — bf16x4 vectors (R20-proven construct)
        #pragma unroll
        for (int ct = 0; ct < 4; ++ct) {
          bf16x4 pk = { (bf16_t)s[j][ct][0], (bf16_t)s[j][ct][1],
                        (bf16_t)s[j][ct][2], (bf16_t)s[j][ct][3] };
          *reinterpret_cast<bf16x4*>(&Plds[w * 4096 + swz(j * 16 + qh, (ct * 16 + g * 4) * 2)]) = pk;
        }
      }

      #pragma unroll
      for (int ks = 0; ks < 2; ++ks) {
        const int kb = (ks * 32 + g * 8) * 2;
        bf16x8 pf0 = *reinterpret_cast<const bf16x8*>(&Plds[w * 4096 + swz(qh, kb)]);
        bf16x8 pf1 = *reinterpret_cast<const bf16x8*>(&Plds[w * 4096 + swz(16 + qh, kb)]);
        #pragma unroll
        for (int dct = 0; dct < 4; ++dct) {
          bf16x8 vf = *reinterpret_cast<const bf16x8*>(&Vlds[swz(dct * 16 + qh, kb)]);
          acc[0][dct] = mfma16(pf0, vf, acc[0][dct]);
          acc[1][dct] = mfma16(pf1, vf, acc[1][dct]);
        }
      }
    }
  }

  #pragma unroll
  for (int j = 0; j < 2; ++j) {
    const float inv = 1.0f / lsum[j];
    float invr[4];
    #pragma unroll
    for (int r = 0; r < 4; ++r) invr[r] = __shfl(inv, g * 4 + r, 64);
    #pragma unroll
    for (int dct = 0; dct < 4; ++dct) {
      const int col = h * DKH + dct * 16 + qh;
      #pragma unroll
      for (int r = 0; r < 4; ++r) {
        const int q = wq0 + j * 16 + g * 4 + r;
        AO[(rb + q) * DMODEL + col] = (bf16_t)(acc[j][dct][r] * invr[r]);
      }
    }
  }
}

extern "C" void kernel_launch(void* const* d_in, const int* in_sizes, int n_in,
                              void* d_out, int out_size, void* d_ws, size_t ws_size,
                              hipStream_t stream)
{
  const float* query = (const float*)d_in[0];
  const float* keyin = (const float*)d_in[1];
  const int*   mask  = (const int*)d_in[2];
  const float* Wq = (const float*)d_in[3];
  const float* bq = (const float*)d_in[4];
  const float* Wk = (const float*)d_in[5];
  const float* bk = (const float*)d_in[6];
  const float* Wv = (const float*)d_in[7];
  const float* bv = (const float*)d_in[8];
  const float* Wo = (const float*)d_in[9];
  const float* bo = (const float*)d_in[10];
  float* out = (float*)d_out;

  bf16_t* Qp = (bf16_t*)d_ws;
  bf16_t* Kp = Qp + (size_t)MROWS * DMODEL;
  bf16_t* Vt = Kp + (size_t)MROWS * DMODEL;
  bf16_t* AO = Vt + (size_t)MROWS * DMODEL;
  unsigned long long* Mpk = (unsigned long long*)(AO + (size_t)MROWS * DMODEL);
  bf16_t* Wtq = (bf16_t*)(Mpk + MWORDS);
  bf16_t* Wtk = Wtq + 512 * 256;
  bf16_t* Wtv = Wtk + 512 * 256;
  bf16_t* Wto = Wtv + 512 * 256;

  dim3 blk(256);

  prep_fused<<<dim3(672), blk, 0, stream>>>(mask, Mpk, Wq, Wk, Wv, Wo, Wtq, Wtk, Wtv, Wto);
  gemm_qkv<<<dim3(2048), blk, 0, stream>>>(query, keyin, Wtq, Wtk, Wtv, bq, bk, bv, Qp, Kp, Vt);

  attn_kernel<<<dim3(NB * NH * (LQ / 128)), blk, 0, stream>>>(Qp, Kp, Vt, Mpk, AO);

  gemm_bias_act<512, false, bf16_t, float><<<dim3(1024), blk, 0, stream>>>(AO, Wto, bo, out, 1.0f);
}

// Round 23
// 88.906 us; speedup vs baseline: 1.3538x; 1.0361x over previous
//
#include <hip/hip_runtime.h>
#include <hip/hip_bf16.h>
#include <type_traits>

typedef __bf16 bf16_t;
typedef __bf16 bf16x4 __attribute__((ext_vector_type(4)));
typedef __bf16 bf16x8 __attribute__((ext_vector_type(8)));
typedef float  f32x4  __attribute__((ext_vector_type(4)));

__device__ __forceinline__ f32x4 mfma16(bf16x8 a, bf16x8 b, f32x4 c) {
  return __builtin_amdgcn_mfma_f32_16x16x32_bf16(a, b, c, 0, 0, 0);
}

static constexpr int NB = 8;
static constexpr int LQ = 1024;
static constexpr int LKk = 1024;
static constexpr int DMODEL = 512;
static constexpr int NH = 8;
static constexpr int DKH = 64;
static constexpr int MROWS = NB * LQ;   // 8192
static constexpr int MWORDS = NB * LQ * (LKk / 64);  // 131072 u64 words
#define KSCALE 0.1803368801111204f

// swizzled byte offset for [R][128B] row-major LDS tiles (G4 XOR swizzle)
__device__ __forceinline__ int swz(int row, int byte) {
  return row * 128 + (byte ^ ((row & 7) << 4));
}

// ------- one-time weight transpose+convert: W f32 [K][N] -> Wt bf16 [N][K] --
__device__ __forceinline__ void wt_tile(const float* __restrict__ W, bf16_t* __restrict__ Wt,
                                        int K, int N, int kt, int nt, int t) {
  __shared__ bf16_t T[64][72];
  const int k0 = kt * 64, n0 = nt * 64;
  const int kr = t >> 2, c0 = (t & 3) * 16;
  const float4* src = reinterpret_cast<const float4*>(W + (size_t)(k0 + kr) * N + n0 + c0);
  #pragma unroll
  for (int j = 0; j < 4; ++j) {
    float4 f = src[j];
    T[c0 + j * 4 + 0][kr] = (bf16_t)f.x;
    T[c0 + j * 4 + 1][kr] = (bf16_t)f.y;
    T[c0 + j * 4 + 2][kr] = (bf16_t)f.z;
    T[c0 + j * 4 + 3][kr] = (bf16_t)f.w;
  }
  __syncthreads();
  const int nr = t >> 2, kc0 = (t & 3) * 16;
  bf16_t* dst = Wt + (size_t)(n0 + nr) * K + k0 + kc0;
  #pragma unroll
  for (int j = 0; j < 2; ++j)
    *reinterpret_cast<bf16x8*>(dst + j * 8) =
        *reinterpret_cast<const bf16x8*>(&T[nr][kc0 + j * 8]);
}

// ------- fused prep: blocks 0..511 mask_pack | 512..671 weight_prep --------
__global__ __launch_bounds__(256)
void prep_fused(const int* __restrict__ mask, unsigned long long* __restrict__ mpk,
                const float* __restrict__ Wq, const float* __restrict__ Wk,
                const float* __restrict__ Wv, const float* __restrict__ Wo,
                bf16_t* __restrict__ Wtq, bf16_t* __restrict__ Wtk,
                bf16_t* __restrict__ Wtv, bf16_t* __restrict__ Wto) {
  const int bid = blockIdx.x, t = threadIdx.x;
  if (bid < 512) {
    const int wd = bid * 256 + t;
    const int4* base = reinterpret_cast<const int4*>(mask + (size_t)wd * 64);
    unsigned long long bits = 0;
    #pragma unroll
    for (int i = 0; i < 16; ++i) {
      int4 v = base[i];
      bits |= (unsigned long long)(v.x != 0) << (4 * i);
      bits |= (unsigned long long)(v.y != 0) << (4 * i + 1);
      bits |= (unsigned long long)(v.z != 0) << (4 * i + 2);
      bits |= (unsigned long long)(v.w != 0) << (4 * i + 3);
    }
    mpk[wd] = bits;
  } else {
    const int bidx = bid - 512;
    if (bidx < 32)        wt_tile(Wq, Wtq, 256, 512, bidx >> 3, bidx & 7, t);
    else if (bidx < 64)   wt_tile(Wk, Wtk, 256, 512, (bidx - 32) >> 3, bidx & 7, t);
    else if (bidx < 96)   wt_tile(Wv, Wtv, 256, 512, (bidx - 64) >> 3, bidx & 7, t);
    else                  wt_tile(Wo, Wto, 512, 512, (bidx - 96) >> 3, bidx & 7, t);
  }
}

// ---- GEMM (R14-proven 64^2 tile, 1024 blocks): C = postscale*act(A@Wt^T+b) --
template<int K, bool RELU, typename AT, typename OT>
__global__ __launch_bounds__(256)
void gemm_bias_act(const AT* __restrict__ A, const bf16_t* __restrict__ Wt,
                   const float* __restrict__ bias, OT* __restrict__ C,
                   float postscale)
{
  constexpr int N = 512;
  __shared__ alignas(16) char Alds[64 * 128];
  __shared__ alignas(16) char Wlds[64 * 128];
  const int t = threadIdx.x;
  const int l = t & 63, w = t >> 6;
  const int xcd = blockIdx.x & 7, idx = blockIdx.x >> 3;
  const int m0 = (xcd * 16 + (idx >> 3)) * 64, n0 = (idx & 7) * 64;

  f32x4 acc[4] = {};
  for (int k0 = 0; k0 < K; k0 += 64) {
    __syncthreads();
    if constexpr (std::is_same<AT, float>::value) {
      const int row = t >> 2, c0 = (t & 3) * 16;
      const float4* ap = reinterpret_cast<const float4*>(A + (size_t)(m0 + row) * K + k0 + c0);
      #pragma unroll
      for (int j = 0; j < 4; ++j) {
        float4 f = ap[j];
        bf16x4 o = { (bf16_t)f.x, (bf16_t)f.y, (bf16_t)f.z, (bf16_t)f.w };
        *reinterpret_cast<bf16x4*>(&Alds[swz(row, (c0 + j * 4) * 2)]) = o;
      }
    } else {
      const int row = t >> 2, cb = ((2 * t) & 7) * 16;
      const bf16_t* src = A + (size_t)(m0 + row) * K + k0 + cb / 2;
      *reinterpret_cast<bf16x8*>(&Alds[swz(row, cb)]) = *reinterpret_cast<const bf16x8*>(src);
      *reinterpret_cast<bf16x8*>(&Alds[swz(row, cb + 16)]) = *reinterpret_cast<const bf16x8*>(src + 8);
    }
    {
      const int row = t >> 2, cb = ((2 * t) & 7) * 16;
      const bf16_t* src = Wt + (size_t)(n0 + row) * K + k0 + cb / 2;
      *reinterpret_cast<bf16x8*>(&Wlds[swz(row, cb)]) = *reinterpret_cast<const bf16x8*>(src);
      *reinterpret_cast<bf16x8*>(&Wlds[swz(row, cb + 16)]) = *reinterpret_cast<const bf16x8*>(src + 8);
    }
    __syncthreads();
    #pragma unroll
    for (int ks = 0; ks < 2; ++ks) {
      const int kb = (ks * 32 + ((l >> 4) * 8)) * 2;
      const int arow = w * 16 + (l & 15);
      bf16x8 af = *reinterpret_cast<const bf16x8*>(&Alds[swz(arow, kb)]);
      #pragma unroll
      for (int ct = 0; ct < 4; ++ct) {
        const int brow = ct * 16 + (l & 15);
        bf16x8 bfr = *reinterpret_cast<const bf16x8*>(&Wlds[swz(brow, kb)]);
        acc[ct] = mfma16(af, bfr, acc[ct]);
      }
    }
  }
  #pragma unroll
  for (int ct = 0; ct < 4; ++ct) {
    const int col = n0 + ct * 16 + (l & 15);
    const float bv = bias[col];
    #pragma unroll
    for (int r = 0; r < 4; ++r) {
      const int row = m0 + w * 16 + ((l >> 4) * 4) + r;
      float x = acc[ct][r] + bv;
      if constexpr (RELU) x = fmaxf(x, 0.f);
      C[(size_t)row * N + col] = (OT)(x * postscale);
    }
  }
}

// ------- merged K+V projection (R14-proven); V written TRANSPOSED -----------
__global__ __launch_bounds__(256)
void gemm_kv(const float* __restrict__ A, const bf16_t* __restrict__ Wtk,
             const bf16_t* __restrict__ Wtv, const float* __restrict__ bk,
             const float* __restrict__ bv, bf16_t* __restrict__ Ck,
             bf16_t* __restrict__ Vt)
{
  constexpr int K = 256, N = 512;
  __shared__ alignas(16) char Alds[64 * 128];
  __shared__ alignas(16) char Wk_lds[64 * 128];
  __shared__ alignas(16) char Wv_lds[64 * 128];
  const int t = threadIdx.x;
  const int l = t & 63, w = t >> 6;
  const int xcd = blockIdx.x & 7, idx = blockIdx.x >> 3;
  const int m0 = (xcd * 16 + (idx >> 3)) * 64, n0 = (idx & 7) * 64;

  f32x4 acck[4] = {}, accv[4] = {};
  for (int k0 = 0; k0 < K; k0 += 64) {
    __syncthreads();
    {
      const int row = t >> 2, c0 = (t & 3) * 16;
      const float4* ap = reinterpret_cast<const float4*>(A + (size_t)(m0 + row) * K + k0 + c0);
      #pragma unroll
      for (int j = 0; j < 4; ++j) {
        float4 f = ap[j];
        bf16x4 o = { (bf16_t)f.x, (bf16_t)f.y, (bf16_t)f.z, (bf16_t)f.w };
        *reinterpret_cast<bf16x4*>(&Alds[swz(row, (c0 + j * 4) * 2)]) = o;
      }
    }
    {
      const int row = t >> 2, cb = ((2 * t) & 7) * 16;
      const bf16_t* sk = Wtk + (size_t)(n0 + row) * K + k0 + cb / 2;
      const bf16_t* sv = Wtv + (size_t)(n0 + row) * K + k0 + cb / 2;
      *reinterpret_cast<bf16x8*>(&Wk_lds[swz(row, cb)]) = *reinterpret_cast<const bf16x8*>(sk);
      *reinterpret_cast<bf16x8*>(&Wk_lds[swz(row, cb + 16)]) = *reinterpret_cast<const bf16x8*>(sk + 8);
      *reinterpret_cast<bf16x8*>(&Wv_lds[swz(row, cb)]) = *reinterpret_cast<const bf16x8*>(sv);
      *reinterpret_cast<bf16x8*>(&Wv_lds[swz(row, cb + 16)]) = *reinterpret_cast<const bf16x8*>(sv + 8);
    }
    __syncthreads();
    #pragma unroll
    for (int ks = 0; ks < 2; ++ks) {
      const int kb = (ks * 32 + ((l >> 4) * 8)) * 2;
      const int arow = w * 16 + (l & 15);
      bf16x8 af = *reinterpret_cast<const bf16x8*>(&Alds[swz(arow, kb)]);
      #pragma unroll
      for (int ct = 0; ct < 4; ++ct) {
        const int brow = ct * 16 + (l & 15);
        bf16x8 bk8 = *reinterpret_cast<const bf16x8*>(&Wk_lds[swz(brow, kb)]);
        bf16x8 bv8 = *reinterpret_cast<const bf16x8*>(&Wv_lds[swz(brow, kb)]);
        acck[ct] = mfma16(af, bk8, acck[ct]);
        accv[ct] = mfma16(af, bv8, accv[ct]);
      }
    }
  }
  const int row0 = m0 + w * 16 + ((l >> 4) * 4);
  const int vb = row0 >> 10;
  const int kv = row0 & 1023;
  #pragma unroll
  for (int ct = 0; ct < 4; ++ct) {
    const int col = n0 + ct * 16 + (l & 15);
    const float bkv = bk[col], bvv = bv[col];
    #pragma unroll
    for (int r = 0; r < 4; ++r)
      Ck[(size_t)(row0 + r) * N + col] = (bf16_t)(fmaxf(acck[ct][r] + bkv, 0.f) * KSCALE);
    bf16x4 vv;
    #pragma unroll
    for (int r = 0; r < 4; ++r) vv[r] = (bf16_t)fmaxf(accv[ct][r] + bvv, 0.f);
    bf16_t* dst = Vt + (((size_t)vb * NH + (col >> 6)) * DKH + (col & 63)) * LKk + kv;
    *reinterpret_cast<bf16x4*>(dst) = vv;
  }
}

// -- flash attention: R22-verified (KVBLK=128, QBLK=32, bf16x4 P-stores) -----
__global__ __launch_bounds__(256)
void attn_kernel(const bf16_t* __restrict__ Qp, const bf16_t* __restrict__ Kp,
                 const bf16_t* __restrict__ Vt, const unsigned long long* __restrict__ Mpk,
                 bf16_t* __restrict__ AO)
{
  __shared__ alignas(16) char K1[8192], K2[8192], V1[8192], V2[8192];
  __shared__ alignas(16) char Plds[4 * 32 * 128];
  const int t = threadIdx.x, l = t & 63, w = t >> 6;
  const int g = l >> 4, qh = l & 15;
  const int bid = (blockIdx.x & 7) * 64 + (blockIdx.x >> 3);
  const int qt = bid & 7, h = (bid >> 3) & 7, b = bid >> 6;
  const int wq0 = qt * 128 + w * 32;
  const size_t rb = (size_t)b * LQ;
  const bf16_t* vtb = Vt + ((size_t)b * NH + h) * DKH * LKk;

  bf16x8 qf[2][2];
  #pragma unroll
  for (int j = 0; j < 2; ++j)
    #pragma unroll
    for (int ks = 0; ks < 2; ++ks)
      qf[j][ks] = *reinterpret_cast<const bf16x8*>(
          Qp + (rb + wq0 + j * 16 + qh) * DMODEL + h * DKH + ks * 32 + g * 8);

  const unsigned long long* mrow0 = Mpk + (rb + wq0 + qh) * (LKk / 64);
  const unsigned long long* mrow1 = Mpk + (rb + wq0 + 16 + qh) * (LKk / 64);

  f32x4 acc[2][4] = {};
  float mrun[2] = { -1e30f, -1e30f }, lsum[2] = { 0.f, 0.f };

  const int srow = t >> 2, scb = ((2 * t) & 7) * 16;

  for (int kv0 = 0; kv0 < LKk; kv0 += 128) {
    __syncthreads();
    {
      const bf16_t* sk1 = Kp + (rb + kv0 + srow) * DMODEL + h * DKH + scb / 2;
      const bf16_t* sk2 = sk1 + (size_t)64 * DMODEL;
      *reinterpret_cast<bf16x8*>(&K1[swz(srow, scb)]) = *reinterpret_cast<const bf16x8*>(sk1);
      *reinterpret_cast<bf16x8*>(&K1[swz(srow, scb + 16)]) = *reinterpret_cast<const bf16x8*>(sk1 + 8);
      *reinterpret_cast<bf16x8*>(&K2[swz(srow, scb)]) = *reinterpret_cast<const bf16x8*>(sk2);
      *reinterpret_cast<bf16x8*>(&K2[swz(srow, scb + 16)]) = *reinterpret_cast<const bf16x8*>(sk2 + 8);
      const bf16_t* sv1 = vtb + (size_t)srow * LKk + kv0 + scb / 2;
      const bf16_t* sv2 = sv1 + 64;
      *reinterpret_cast<bf16x8*>(&V1[swz(srow, scb)]) = *reinterpret_cast<const bf16x8*>(sv1);
      *reinterpret_cast<bf16x8*>(&V1[swz(srow, scb + 16)]) = *reinterpret_cast<const bf16x8*>(sv1 + 8);
      *reinterpret_cast<bf16x8*>(&V2[swz(srow, scb)]) = *reinterpret_cast<const bf16x8*>(sv2);
      *reinterpret_cast<bf16x8*>(&V2[swz(srow, scb + 16)]) = *reinterpret_cast<const bf16x8*>(sv2 + 8);
    }
    __syncthreads();

    #pragma unroll
    for (int half = 0; half < 2; ++half) {
      const char* Klds = half ? K2 : K1;
      const char* Vlds = half ? V2 : V1;
      const int kvh = (kv0 >> 6) + half;
      const unsigned long long mw[2] = { mrow0[kvh], mrow1[kvh] };

      f32x4 s[2][4] = {};
      #pragma unroll
      for (int ks = 0; ks < 2; ++ks) {
        const int kb = (ks * 32 + g * 8) * 2;
        #pragma unroll
        for (int ct = 0; ct < 4; ++ct) {
          bf16x8 kf = *reinterpret_cast<const bf16x8*>(&Klds[swz(ct * 16 + qh, kb)]);
          s[0][ct] = mfma16(kf, qf[0][ks], s[0][ct]);
          s[1][ct] = mfma16(kf, qf[1][ks], s[1][ct]);
        }
      }

      #pragma unroll
      for (int j = 0; j < 2; ++j) {
        float rmax = -1e30f;
        #pragma unroll
        for (int ct = 0; ct < 4; ++ct) {
          #pragma unroll
          for (int r = 0; r < 4; ++r) {
            float x = ((mw[j] >> (ct * 16 + g * 4 + r)) & 1) ? s[j][ct][r] : -1e8f;
            s[j][ct][r] = x;
            rmax = fmaxf(rmax, x);
          }
        }
        rmax = fmaxf(rmax, __shfl_xor(rmax, 16));
        rmax = fmaxf(rmax, __shfl_xor(rmax, 32));
        const float newm = fmaxf(mrun[j], rmax);

        if (__any(newm > mrun[j])) {
          const float scale = __builtin_amdgcn_exp2f(mrun[j] - newm);
          lsum[j] *= scale;
          #pragma unroll
          for (int r = 0; r < 4; ++r) {
            const float sr = __shfl(scale, g * 4 + r, 64);
            #pragma unroll
            for (int dct = 0; dct < 4; ++dct) acc[j][dct][r] *= sr;
          }
          mrun[j] = newm;
        }

        float psum = 0.f;
        #pragma unroll
        for (int ct = 0; ct < 4; ++ct) {
          #pragma unroll
          for (int r = 0; r < 4; ++r) {
            const float pv = __builtin_amdgcn_exp2f(s[j][ct][r] - mrun[j]);
            s[j][ct][r] = pv;
            psum += pv;
          }
        }
        psum += __shfl_xor(psum, 16);
        psum += __shfl_xor(psum, 32);
        lsum[j] += psum;

        // P stores — bf16x4 vectors (R20/R22-proven construct)
        #pragma unroll
        for (int ct = 0; ct < 4; ++ct) {
          bf16x4 pk = { (bf16_t)s[j][ct][0], (bf16_t)s[j][ct][1],
                        (bf16_t)s[j][ct][2], (bf16_t)s[j][ct][3] };
          *reinterpret_cast<bf16x4*>(&Plds[w * 4096 + swz(j * 16 + qh, (ct * 16 + g * 4) * 2)]) = pk;
        }
      }

      #pragma unroll
      for (int ks = 0; ks < 2; ++ks) {
        const int kb = (ks * 32 + g * 8) * 2;
        bf16x8 pf0 = *reinterpret_cast<const bf16x8*>(&Plds[w * 4096 + swz(qh, kb)]);
        bf16x8 pf1 = *reinterpret_cast<const bf16x8*>(&Plds[w * 4096 + swz(16 + qh, kb)]);
        #pragma unroll
        for (int dct = 0; dct < 4; ++dct) {
          bf16x8 vf = *reinterpret_cast<const bf16x8*>(&Vlds[swz(dct * 16 + qh, kb)]);
          acc[0][dct] = mfma16(pf0, vf, acc[0][dct]);
          acc[1][dct] = mfma16(pf1, vf, acc[1][dct]);
        }
      }
    }
  }

  #pragma unroll
  for (int j = 0; j < 2; ++j) {
    const float inv = 1.0f / lsum[j];
    float invr[4];
    #pragma unroll
    for (int r = 0; r < 4; ++r) invr[r] = __shfl(inv, g * 4 + r, 64);
    #pragma unroll
    for (int dct = 0; dct < 4; ++dct) {
      const int col = h * DKH + dct * 16 + qh;
      #pragma unroll
      for (int r = 0; r < 4; ++r) {
        const int q = wq0 + j * 16 + g * 4 + r;
        AO[(rb + q) * DMODEL + col] = (bf16_t)(acc[j][dct][r] * invr[r]);
      }
    }
  }
}

extern "C" void kernel_launch(void* const* d_in, const int* in_sizes, int n_in,
                              void* d_out, int out_size, void* d_ws, size_t ws_size,
                              hipStream_t stream)
{
  const float* query = (const float*)d_in[0];
  const float* keyin = (const float*)d_in[1];
  const int*   mask  = (const int*)d_in[2];
  const float* Wq = (const float*)d_in[3];
  const float* bq = (const float*)d_in[4];
  const float* Wk = (const float*)d_in[5];
  const float* bk = (const float*)d_in[6];
  const float* Wv = (const float*)d_in[7];
  const float* bv = (const float*)d_in[8];
  const float* Wo = (const float*)d_in[9];
  const float* bo = (const float*)d_in[10];
  float* out = (float*)d_out;

  bf16_t* Qp = (bf16_t*)d_ws;
  bf16_t* Kp = Qp + (size_t)MROWS * DMODEL;
  bf16_t* Vt = Kp + (size_t)MROWS * DMODEL;
  bf16_t* AO = Vt + (size_t)MROWS * DMODEL;
  unsigned long long* Mpk = (unsigned long long*)(AO + (size_t)MROWS * DMODEL);
  bf16_t* Wtq = (bf16_t*)(Mpk + MWORDS);
  bf16_t* Wtk = Wtq + 512 * 256;
  bf16_t* Wtv = Wtk + 512 * 256;
  bf16_t* Wto = Wtv + 512 * 256;

  dim3 blk(256);

  prep_fused<<<dim3(672), blk, 0, stream>>>(mask, Mpk, Wq, Wk, Wv, Wo, Wtq, Wtk, Wtv, Wto);
  gemm_bias_act<256, true, float, bf16_t><<<dim3(1024), blk, 0, stream>>>(query, Wtq, bq, Qp, 1.0f);
  gemm_kv<<<dim3(1024), blk, 0, stream>>>(keyin, Wtk, Wtv, bk, bv, Kp, Vt);

  attn_kernel<<<dim3(NB * NH * (LQ / 128)), blk, 0, stream>>>(Qp, Kp, Vt, Mpk, AO);

  gemm_bias_act<512, false, bf16_t, float><<<dim3(1024), blk, 0, stream>>>(AO, Wto, bo, out, 1.0f);
}

// Round 24
// 87.258 us; speedup vs baseline: 1.3793x; 1.0189x over previous
//
#include <hip/hip_runtime.h>
#include <hip/hip_bf16.h>
#include <type_traits>

typedef __bf16 bf16_t;
typedef __bf16 bf16x4 __attribute__((ext_vector_type(4)));
typedef __bf16 bf16x8 __attribute__((ext_vector_type(8)));
typedef float  f32x4  __attribute__((ext_vector_type(4)));

__device__ __forceinline__ f32x4 mfma16(bf16x8 a, bf16x8 b, f32x4 c) {
  return __builtin_amdgcn_mfma_f32_16x16x32_bf16(a, b, c, 0, 0, 0);
}

static constexpr int NB = 8;
static constexpr int LQ = 1024;
static constexpr int LKk = 1024;
static constexpr int DMODEL = 512;
static constexpr int NH = 8;
static constexpr int DKH = 64;
static constexpr int MROWS = NB * LQ;   // 8192
static constexpr int MWORDS = NB * LQ * (LKk / 64);  // 131072 u64 words
#define KSCALE 0.1803368801111204f

// swizzled byte offset for [R][128B] row-major LDS tiles (G4 XOR swizzle)
__device__ __forceinline__ int swz(int row, int byte) {
  return row * 128 + (byte ^ ((row & 7) << 4));
}

// ------- one-time weight transpose+convert: W f32 [K][N] -> Wt bf16 [N][K] --
__device__ __forceinline__ void wt_tile(const float* __restrict__ W, bf16_t* __restrict__ Wt,
                                        int K, int N, int kt, int nt, int t) {
  __shared__ bf16_t T[64][72];
  const int k0 = kt * 64, n0 = nt * 64;
  const int kr = t >> 2, c0 = (t & 3) * 16;
  const float4* src = reinterpret_cast<const float4*>(W + (size_t)(k0 + kr) * N + n0 + c0);
  #pragma unroll
  for (int j = 0; j < 4; ++j) {
    float4 f = src[j];
    T[c0 + j * 4 + 0][kr] = (bf16_t)f.x;
    T[c0 + j * 4 + 1][kr] = (bf16_t)f.y;
    T[c0 + j * 4 + 2][kr] = (bf16_t)f.z;
    T[c0 + j * 4 + 3][kr] = (bf16_t)f.w;
  }
  __syncthreads();
  const int nr = t >> 2, kc0 = (t & 3) * 16;
  bf16_t* dst = Wt + (size_t)(n0 + nr) * K + k0 + kc0;
  #pragma unroll
  for (int j = 0; j < 2; ++j)
    *reinterpret_cast<bf16x8*>(dst + j * 8) =
        *reinterpret_cast<const bf16x8*>(&T[nr][kc0 + j * 8]);
}

// ------- fused prep: blocks 0..511 mask_pack | 512..671 weight_prep --------
__global__ __launch_bounds__(256)
void prep_fused(const int* __restrict__ mask, unsigned long long* __restrict__ mpk,
                const float* __restrict__ Wq, const float* __restrict__ Wk,
                const float* __restrict__ Wv, const float* __restrict__ Wo,
                bf16_t* __restrict__ Wtq, bf16_t* __restrict__ Wtk,
                bf16_t* __restrict__ Wtv, bf16_t* __restrict__ Wto) {
  const int bid = blockIdx.x, t = threadIdx.x;
  if (bid < 512) {
    const int wd = bid * 256 + t;
    const int4* base = reinterpret_cast<const int4*>(mask + (size_t)wd * 64);
    unsigned long long bits = 0;
    #pragma unroll
    for (int i = 0; i < 16; ++i) {
      int4 v = base[i];
      bits |= (unsigned long long)(v.x != 0) << (4 * i);
      bits |= (unsigned long long)(v.y != 0) << (4 * i + 1);
      bits |= (unsigned long long)(v.z != 0) << (4 * i + 2);
      bits |= (unsigned long long)(v.w != 0) << (4 * i + 3);
    }
    mpk[wd] = bits;
  } else {
    const int bidx = bid - 512;
    if (bidx < 32)        wt_tile(Wq, Wtq, 256, 512, bidx >> 3, bidx & 7, t);
    else if (bidx < 64)   wt_tile(Wk, Wtk, 256, 512, (bidx - 32) >> 3, bidx & 7, t);
    else if (bidx < 96)   wt_tile(Wv, Wtv, 256, 512, (bidx - 64) >> 3, bidx & 7, t);
    else                  wt_tile(Wo, Wto, 512, 512, (bidx - 96) >> 3, bidx & 7, t);
  }
}

// ---- GEMM: 64^2 tile, 1024 blocks, BK=128 (two 64-k halves per barrier) ----
template<int K, bool RELU, typename AT, typename OT>
__global__ __launch_bounds__(256)
void gemm_bias_act(const AT* __restrict__ A, const bf16_t* __restrict__ Wt,
                   const float* __restrict__ bias, OT* __restrict__ C,
                   float postscale)
{
  constexpr int N = 512;
  __shared__ alignas(16) char A1[8192], A2[8192], W1[8192], W2[8192];
  const int t = threadIdx.x;
  const int l = t & 63, w = t >> 6;
  const int xcd = blockIdx.x & 7, idx = blockIdx.x >> 3;
  const int m0 = (xcd * 16 + (idx >> 3)) * 64, n0 = (idx & 7) * 64;

  f32x4 acc[4] = {};
  for (int k0 = 0; k0 < K; k0 += 128) {
    __syncthreads();
    if constexpr (std::is_same<AT, float>::value) {
      const int row = t >> 2, c0 = (t & 3) * 16;
      const float4* ap = reinterpret_cast<const float4*>(A + (size_t)(m0 + row) * K + k0 + c0);
      const float4* ap2 = reinterpret_cast<const float4*>(A + (size_t)(m0 + row) * K + k0 + 64 + c0);
      #pragma unroll
      for (int j = 0; j < 4; ++j) {
        float4 f = ap[j], f2 = ap2[j];
        bf16x4 o  = { (bf16_t)f.x,  (bf16_t)f.y,  (bf16_t)f.z,  (bf16_t)f.w };
        bf16x4 o2 = { (bf16_t)f2.x, (bf16_t)f2.y, (bf16_t)f2.z, (bf16_t)f2.w };
        *reinterpret_cast<bf16x4*>(&A1[swz(row, (c0 + j * 4) * 2)]) = o;
        *reinterpret_cast<bf16x4*>(&A2[swz(row, (c0 + j * 4) * 2)]) = o2;
      }
    } else {
      const int row = t >> 2, cb = ((2 * t) & 7) * 16;
      const bf16_t* src = A + (size_t)(m0 + row) * K + k0 + cb / 2;
      *reinterpret_cast<bf16x8*>(&A1[swz(row, cb)]) = *reinterpret_cast<const bf16x8*>(src);
      *reinterpret_cast<bf16x8*>(&A1[swz(row, cb + 16)]) = *reinterpret_cast<const bf16x8*>(src + 8);
      *reinterpret_cast<bf16x8*>(&A2[swz(row, cb)]) = *reinterpret_cast<const bf16x8*>(src + 64);
      *reinterpret_cast<bf16x8*>(&A2[swz(row, cb + 16)]) = *reinterpret_cast<const bf16x8*>(src + 72);
    }
    {
      const int row = t >> 2, cb = ((2 * t) & 7) * 16;
      const bf16_t* src = Wt + (size_t)(n0 + row) * K + k0 + cb / 2;
      *reinterpret_cast<bf16x8*>(&W1[swz(row, cb)]) = *reinterpret_cast<const bf16x8*>(src);
      *reinterpret_cast<bf16x8*>(&W1[swz(row, cb + 16)]) = *reinterpret_cast<const bf16x8*>(src + 8);
      *reinterpret_cast<bf16x8*>(&W2[swz(row, cb)]) = *reinterpret_cast<const bf16x8*>(src + 64);
      *reinterpret_cast<bf16x8*>(&W2[swz(row, cb + 16)]) = *reinterpret_cast<const bf16x8*>(src + 72);
    }
    __syncthreads();
    #pragma unroll
    for (int half = 0; half < 2; ++half) {
      const char* Al = half ? A2 : A1;
      const char* Wl = half ? W2 : W1;
      #pragma unroll
      for (int ks = 0; ks < 2; ++ks) {
        const int kb = (ks * 32 + ((l >> 4) * 8)) * 2;
        const int arow = w * 16 + (l & 15);
        bf16x8 af = *reinterpret_cast<const bf16x8*>(&Al[swz(arow, kb)]);
        #pragma unroll
        for (int ct = 0; ct < 4; ++ct) {
          const int brow = ct * 16 + (l & 15);
          bf16x8 bfr = *reinterpret_cast<const bf16x8*>(&Wl[swz(brow, kb)]);
          acc[ct] = mfma16(af, bfr, acc[ct]);
        }
      }
    }
  }
  #pragma unroll
  for (int ct = 0; ct < 4; ++ct) {
    const int col = n0 + ct * 16 + (l & 15);
    const float bv = bias[col];
    #pragma unroll
    for (int r = 0; r < 4; ++r) {
      const int row = m0 + w * 16 + ((l >> 4) * 4) + r;
      float x = acc[ct][r] + bv;
      if constexpr (RELU) x = fmaxf(x, 0.f);
      C[(size_t)row * N + col] = (OT)(x * postscale);
    }
  }
}

// ------- merged K+V projection (R14-proven); V written TRANSPOSED -----------
__global__ __launch_bounds__(256)
void gemm_kv(const float* __restrict__ A, const bf16_t* __restrict__ Wtk,
             const bf16_t* __restrict__ Wtv, const float* __restrict__ bk,
             const float* __restrict__ bv, bf16_t* __restrict__ Ck,
             bf16_t* __restrict__ Vt)
{
  constexpr int K = 256, N = 512;
  __shared__ alignas(16) char Alds[64 * 128];
  __shared__ alignas(16) char Wk_lds[64 * 128];
  __shared__ alignas(16) char Wv_lds[64 * 128];
  const int t = threadIdx.x;
  const int l = t & 63, w = t >> 6;
  const int xcd = blockIdx.x & 7, idx = blockIdx.x >> 3;
  const int m0 = (xcd * 16 + (idx >> 3)) * 64, n0 = (idx & 7) * 64;

  f32x4 acck[4] = {}, accv[4] = {};
  for (int k0 = 0; k0 < K; k0 += 64) {
    __syncthreads();
    {
      const int row = t >> 2, c0 = (t & 3) * 16;
      const float4* ap = reinterpret_cast<const float4*>(A + (size_t)(m0 + row) * K + k0 + c0);
      #pragma unroll
      for (int j = 0; j < 4; ++j) {
        float4 f = ap[j];
        bf16x4 o = { (bf16_t)f.x, (bf16_t)f.y, (bf16_t)f.z, (bf16_t)f.w };
        *reinterpret_cast<bf16x4*>(&Alds[swz(row, (c0 + j * 4) * 2)]) = o;
      }
    }
    {
      const int row = t >> 2, cb = ((2 * t) & 7) * 16;
      const bf16_t* sk = Wtk + (size_t)(n0 + row) * K + k0 + cb / 2;
      const bf16_t* sv = Wtv + (size_t)(n0 + row) * K + k0 + cb / 2;
      *reinterpret_cast<bf16x8*>(&Wk_lds[swz(row, cb)]) = *reinterpret_cast<const bf16x8*>(sk);
      *reinterpret_cast<bf16x8*>(&Wk_lds[swz(row, cb + 16)]) = *reinterpret_cast<const bf16x8*>(sk + 8);
      *reinterpret_cast<bf16x8*>(&Wv_lds[swz(row, cb)]) = *reinterpret_cast<const bf16x8*>(sv);
      *reinterpret_cast<bf16x8*>(&Wv_lds[swz(row, cb + 16)]) = *reinterpret_cast<const bf16x8*>(sv + 8);
    }
    __syncthreads();
    #pragma unroll
    for (int ks = 0; ks < 2; ++ks) {
      const int kb = (ks * 32 + ((l >> 4) * 8)) * 2;
      const int arow = w * 16 + (l & 15);
      bf16x8 af = *reinterpret_cast<const bf16x8*>(&Alds[swz(arow, kb)]);
      #pragma unroll
      for (int ct = 0; ct < 4; ++ct) {
        const int brow = ct * 16 + (l & 15);
        bf16x8 bk8 = *reinterpret_cast<const bf16x8*>(&Wk_lds[swz(brow, kb)]);
        bf16x8 bv8 = *reinterpret_cast<const bf16x8*>(&Wv_lds[swz(brow, kb)]);
        acck[ct] = mfma16(af, bk8, acck[ct]);
        accv[ct] = mfma16(af, bv8, accv[ct]);
      }
    }
  }
  const int row0 = m0 + w * 16 + ((l >> 4) * 4);
  const int vb = row0 >> 10;
  const int kv = row0 & 1023;
  #pragma unroll
  for (int ct = 0; ct < 4; ++ct) {
    const int col = n0 + ct * 16 + (l & 15);
    const float bkv = bk[col], bvv = bv[col];
    #pragma unroll
    for (int r = 0; r < 4; ++r)
      Ck[(size_t)(row0 + r) * N + col] = (bf16_t)(fmaxf(acck[ct][r] + bkv, 0.f) * KSCALE);
    bf16x4 vv;
    #pragma unroll
    for (int r = 0; r < 4; ++r) vv[r] = (bf16_t)fmaxf(accv[ct][r] + bvv, 0.f);
    bf16_t* dst = Vt + (((size_t)vb * NH + (col >> 6)) * DKH + (col & 63)) * LKk + kv;
    *reinterpret_cast<bf16x4*>(dst) = vv;
  }
}

// -- flash attention: R22 structure + softmax trims:
//    (a) max over ALL s (shift-invariance: masked elements may only raise m,
//        which cancels in p/sum(p)); mask applied post-exp as zeroing.
//    (b) lane-local lsum, cross-lane reduce deferred to epilogue.
//    (c) tree-shaped max for v_max3 fusion.
__global__ __launch_bounds__(256)
void attn_kernel(const bf16_t* __restrict__ Qp, const bf16_t* __restrict__ Kp,
                 const bf16_t* __restrict__ Vt, const unsigned long long* __restrict__ Mpk,
                 bf16_t* __restrict__ AO)
{
  __shared__ alignas(16) char K1[8192], K2[8192], V1[8192], V2[8192];
  __shared__ alignas(16) char Plds[4 * 32 * 128];
  const int t = threadIdx.x, l = t & 63, w = t >> 6;
  const int g = l >> 4, qh = l & 15;
  const int bid = (blockIdx.x & 7) * 64 + (blockIdx.x >> 3);
  const int qt = bid & 7, h = (bid >> 3) & 7, b = bid >> 6;
  const int wq0 = qt * 128 + w * 32;
  const size_t rb = (size_t)b * LQ;
  const bf16_t* vtb = Vt + ((size_t)b * NH + h) * DKH * LKk;

  bf16x8 qf[2][2];
  #pragma unroll
  for (int j = 0; j < 2; ++j)
    #pragma unroll
    for (int ks = 0; ks < 2; ++ks)
      qf[j][ks] = *reinterpret_cast<const bf16x8*>(
          Qp + (rb + wq0 + j * 16 + qh) * DMODEL + h * DKH + ks * 32 + g * 8);

  const unsigned long long* mrow0 = Mpk + (rb + wq0 + qh) * (LKk / 64);
  const unsigned long long* mrow1 = Mpk + (rb + wq0 + 16 + qh) * (LKk / 64);

  f32x4 acc[2][4] = {};
  float mrun[2] = { -1e30f, -1e30f }, lsum[2] = { 0.f, 0.f };  // lsum lane-local

  const int srow = t >> 2, scb = ((2 * t) & 7) * 16;

  for (int kv0 = 0; kv0 < LKk; kv0 += 128) {
    __syncthreads();
    {
      const bf16_t* sk1 = Kp + (rb + kv0 + srow) * DMODEL + h * DKH + scb / 2;
      const bf16_t* sk2 = sk1 + (size_t)64 * DMODEL;
      *reinterpret_cast<bf16x8*>(&K1[swz(srow, scb)]) = *reinterpret_cast<const bf16x8*>(sk1);
      *reinterpret_cast<bf16x8*>(&K1[swz(srow, scb + 16)]) = *reinterpret_cast<const bf16x8*>(sk1 + 8);
      *reinterpret_cast<bf16x8*>(&K2[swz(srow, scb)]) = *reinterpret_cast<const bf16x8*>(sk2);
      *reinterpret_cast<bf16x8*>(&K2[swz(srow, scb + 16)]) = *reinterpret_cast<const bf16x8*>(sk2 + 8);
      const bf16_t* sv1 = vtb + (size_t)srow * LKk + kv0 + scb / 2;
      const bf16_t* sv2 = sv1 + 64;
      *reinterpret_cast<bf16x8*>(&V1[swz(srow, scb)]) = *reinterpret_cast<const bf16x8*>(sv1);
      *reinterpret_cast<bf16x8*>(&V1[swz(srow, scb + 16)]) = *reinterpret_cast<const bf16x8*>(sv1 + 8);
      *reinterpret_cast<bf16x8*>(&V2[swz(srow, scb)]) = *reinterpret_cast<const bf16x8*>(sv2);
      *reinterpret_cast<bf16x8*>(&V2[swz(srow, scb + 16)]) = *reinterpret_cast<const bf16x8*>(sv2 + 8);
    }
    __syncthreads();

    #pragma unroll
    for (int half = 0; half < 2; ++half) {
      const char* Klds = half ? K2 : K1;
      const char* Vlds = half ? V2 : V1;
      const int kvh = (kv0 >> 6) + half;
      const unsigned long long mw[2] = { mrow0[kvh], mrow1[kvh] };

      f32x4 s[2][4] = {};
      #pragma unroll
      for (int ks = 0; ks < 2; ++ks) {
        const int kb = (ks * 32 + g * 8) * 2;
        #pragma unroll
        for (int ct = 0; ct < 4; ++ct) {
          bf16x8 kf = *reinterpret_cast<const bf16x8*>(&Klds[swz(ct * 16 + qh, kb)]);
          s[0][ct] = mfma16(kf, qf[0][ks], s[0][ct]);
          s[1][ct] = mfma16(kf, qf[1][ks], s[1][ct]);
        }
      }

      #pragma unroll
      for (int j = 0; j < 2; ++j) {
        // tree max over ALL 16 values (mask not needed: m cancels in p/sum)
        float t0 = fmaxf(fmaxf(s[j][0][0], s[j][0][1]), fmaxf(s[j][0][2], s[j][0][3]));
        float t1 = fmaxf(fmaxf(s[j][1][0], s[j][1][1]), fmaxf(s[j][1][2], s[j][1][3]));
        float t2 = fmaxf(fmaxf(s[j][2][0], s[j][2][1]), fmaxf(s[j][2][2], s[j][2][3]));
        float t3 = fmaxf(fmaxf(s[j][3][0], s[j][3][1]), fmaxf(s[j][3][2], s[j][3][3]));
        float rmax = fmaxf(fmaxf(t0, t1), fmaxf(t2, t3));
        rmax = fmaxf(rmax, __shfl_xor(rmax, 16));
        rmax = fmaxf(rmax, __shfl_xor(rmax, 32));
        const float newm = fmaxf(mrun[j], rmax);

        if (__any(newm > mrun[j])) {
          const float scale = __builtin_amdgcn_exp2f(mrun[j] - newm);
          lsum[j] *= scale;
          #pragma unroll
          for (int r = 0; r < 4; ++r) {
            const float sr = __shfl(scale, g * 4 + r, 64);
            #pragma unroll
            for (int dct = 0; dct < 4; ++dct) acc[j][dct][r] *= sr;
          }
          mrun[j] = newm;
        }

        float psum = 0.f;
        #pragma unroll
        for (int ct = 0; ct < 4; ++ct) {
          const unsigned nib = (unsigned)(mw[j] >> (ct * 16 + g * 4)) & 0xFu;
          #pragma unroll
          for (int r = 0; r < 4; ++r) {
            float pv = __builtin_amdgcn_exp2f(s[j][ct][r] - mrun[j]);
            pv = ((nib >> r) & 1) ? pv : 0.f;   // mask post-exp
            s[j][ct][r] = pv;
            psum += pv;
          }
        }
        lsum[j] += psum;   // lane-local; cross-lane reduce deferred to epilogue

        // P stores — bf16x4 vectors (R20/R22-proven construct)
        #pragma unroll
        for (int ct = 0; ct < 4; ++ct) {
          bf16x4 pk = { (bf16_t)s[j][ct][0], (bf16_t)s[j][ct][1],
                        (bf16_t)s[j][ct][2], (bf16_t)s[j][ct][3] };
          *reinterpret_cast<bf16x4*>(&Plds[w * 4096 + swz(j * 16 + qh, (ct * 16 + g * 4) * 2)]) = pk;
        }
      }

      #pragma unroll
      for (int ks = 0; ks < 2; ++ks) {
        const int kb = (ks * 32 + g * 8) * 2;
        bf16x8 pf0 = *reinterpret_cast<const bf16x8*>(&Plds[w * 4096 + swz(qh, kb)]);
        bf16x8 pf1 = *reinterpret_cast<const bf16x8*>(&Plds[w * 4096 + swz(16 + qh, kb)]);
        #pragma unroll
        for (int dct = 0; dct < 4; ++dct) {
          bf16x8 vf = *reinterpret_cast<const bf16x8*>(&Vlds[swz(dct * 16 + qh, kb)]);
          acc[0][dct] = mfma16(pf0, vf, acc[0][dct]);
          acc[1][dct] = mfma16(pf1, vf, acc[1][dct]);
        }
      }
    }
  }

  #pragma unroll
  for (int j = 0; j < 2; ++j) {
    // deferred cross-lane lsum reduction (replicas share identical m history)
    float ls = lsum[j];
    ls += __shfl_xor(ls, 16);
    ls += __shfl_xor(ls, 32);
    const float inv = 1.0f / ls;
    float invr[4];
    #pragma unroll
    for (int r = 0; r < 4; ++r) invr[r] = __shfl(inv, g * 4 + r, 64);
    #pragma unroll
    for (int dct = 0; dct < 4; ++dct) {
      const int col = h * DKH + dct * 16 + qh;
      #pragma unroll
      for (int r = 0; r < 4; ++r) {
        const int q = wq0 + j * 16 + g * 4 + r;
        AO[(rb + q) * DMODEL + col] = (bf16_t)(acc[j][dct][r] * invr[r]);
      }
    }
  }
}

extern "C" void kernel_launch(void* const* d_in, const int* in_sizes, int n_in,
                              void* d_out, int out_size, void* d_ws, size_t ws_size,
                              hipStream_t stream)
{
  const float* query = (const float*)d_in[0];
  const float* keyin = (const float*)d_in[1];
  const int*   mask  = (const int*)d_in[2];
  const float* Wq = (const float*)d_in[3];
  const float* bq = (const float*)d_in[4];
  const float* Wk = (const float*)d_in[5];
  const float* bk = (const float*)d_in[6];
  const float* Wv = (const float*)d_in[7];
  const float* bv = (const float*)d_in[8];
  const float* Wo = (const float*)d_in[9];
  const float* bo = (const float*)d_in[10];
  float* out = (float*)d_out;

  bf16_t* Qp = (bf16_t*)d_ws;
  bf16_t* Kp = Qp + (size_t)MROWS * DMODEL;
  bf16_t* Vt = Kp + (size_t)MROWS * DMODEL;
  bf16_t* AO = Vt + (size_t)MROWS * DMODEL;
  unsigned long long* Mpk = (unsigned long long*)(AO + (size_t)MROWS * DMODEL);
  bf16_t* Wtq = (bf16_t*)(Mpk + MWORDS);
  bf16_t* Wtk = Wtq + 512 * 256;
  bf16_t* Wtv = Wtk + 512 * 256;
  bf16_t* Wto = Wtv + 512 * 256;

  dim3 blk(256);

  prep_fused<<<dim3(672), blk, 0, stream>>>(mask, Mpk, Wq, Wk, Wv, Wo, Wtq, Wtk, Wtv, Wto);
  gemm_bias_act<256, true, float, bf16_t><<<dim3(1024), blk, 0, stream>>>(query, Wtq, bq, Qp, 1.0f);
  gemm_kv<<<dim3(1024), blk, 0, stream>>>(keyin, Wtk, Wtv, bk, bv, Kp, Vt);

  attn_kernel<<<dim3(NB * NH * (LQ / 128)), blk, 0, stream>>>(Qp, Kp, Vt, Mpk, AO);

  gemm_bias_act<512, false, bf16_t, float><<<dim3(1024), blk, 0, stream>>>(AO, Wto, bo, out, 1.0f);
}